// Round 14
// baseline (187.117 us; speedup 1.0000x reference)
//
#include <hip/hip_runtime.h>
#include <hip/hip_fp16.h>

#define BN_EPS 1e-5f
#define BCAP 5120     // bucket capacity (mean 4096 edges/bucket)
#define STG_H 96      // staged edges, gh64_mm3 (4 nodes/block, mean 64, +4sigma)
#define STG_C 160     // staged edges, gather_cls (8 nodes/block, mean 128, +2.8sigma)

__device__ __forceinline__ unsigned f2u(float a, float b) {
  __half2 h = __floats2half2_rn(a, b);
  return *reinterpret_cast<unsigned*>(&h);
}
__device__ __forceinline__ __half2 uh2(unsigned u) {
  return *reinterpret_cast<__half2*>(&u);
}
__device__ __forceinline__ float2 h22f2(__half2 h) { return __half22float2(h); }
__device__ __forceinline__ __half2 h2shfl_xor(__half2 v, int m) {
  int i = *reinterpret_cast<int*>(&v);
  i = __shfl_xor(i, m);
  return *reinterpret_cast<__half2*>(&i);
}

// ============ prep: block 0 computes BN constants; other blocks zero bcur[0..NB] ============
__global__ void prep(const float* __restrict__ b1, const float* __restrict__ g1,
                     const float* __restrict__ be1, const float* __restrict__ rm1,
                     const float* __restrict__ rv1,
                     const float* __restrict__ b2, const float* __restrict__ g2,
                     const float* __restrict__ be2, const float* __restrict__ rm2,
                     const float* __restrict__ rv2,
                     const float* __restrict__ b3, const float* __restrict__ g3,
                     const float* __restrict__ be3, const float* __restrict__ rm3,
                     const float* __restrict__ rv3,
                     float* __restrict__ bn, int* __restrict__ bcur, int NB) {
  if (blockIdx.x == 0) {
    const int t = threadIdx.x;
    if (t < 64) {
      const float s = g1[t] * rsqrtf(rv1[t] + BN_EPS);
      bn[t] = s;
      bn[64 + t] = (b1[t] - rm1[t]) * s + be1[t];
    } else if (t < 128) {
      const int c = t - 64;
      const float s = g2[c] * rsqrtf(rv2[c] + BN_EPS);
      bn[128 + c] = s;
      bn[192 + c] = (b2[c] - rm2[c]) * s + be2[c];
    } else if (t < 160) {
      const int c = t - 128;
      const float s = g3[c] * rsqrtf(rv3[c] + BN_EPS);
      bn[256 + c] = s;
      bn[288 + c] = (b3[c] - rm3[c]) * s + be3[c];
    }
  } else {
    const int i = (blockIdx.x - 1) * 256 + threadIdx.x;
    if (i <= NB) bcur[i] = 0;
  }
}

// ============ Phase 1: partition edges into per-bucket regions (bucket = dst>>8) ============
__global__ void p1_partition(const int* __restrict__ ei, int* __restrict__ bucketbuf,
                             int* __restrict__ bcur, int E_, int NB) {
  __shared__ int pk[4096];
  __shared__ short bk[4096];
  __shared__ int hist[512];
  __shared__ int bbase[512];
  const int tid = threadIdx.x;
  const int e0 = blockIdx.x * 4096;
  const int ecount = min(4096, E_ - e0);
  for (int i = tid; i < NB; i += 256) hist[i] = 0;
  __syncthreads();
  for (int i = tid; i < ecount; i += 256) {
    const int s = ei[e0 + i];
    const int d = ei[(size_t)E_ + e0 + i];
    pk[i] = ((d & 255) << 24) | s;   // src < 2^24 (N = 100000)
    const int b = d >> 8;
    bk[i] = (short)b;
    atomicAdd(&hist[b], 1);
  }
  __syncthreads();
  for (int i = tid; i < NB; i += 256) {
    const int c = hist[i];
    bbase[i] = c ? atomicAdd(&bcur[i], c) : 0;
    hist[i] = 0;
  }
  __syncthreads();
  for (int i = tid; i < ecount; i += 256) {
    const int b = bk[i];
    const int slot = bbase[b] + atomicAdd(&hist[b], 1);
    bucketbuf[(size_t)b * BCAP + slot] = pk[i];
  }
}

// ============ Phase 2: per-bucket counting sort; atomic global base; emits rbeg/rend, dinv, xs ============
__global__ void p2_sort(const int* __restrict__ bucketbuf, const int* __restrict__ bcur,
                        int* __restrict__ gcursor, int* __restrict__ edata,
                        int* __restrict__ rbeg, int* __restrict__ rend,
                        float* __restrict__ dinv, const float* __restrict__ x,
                        __half2* __restrict__ xs, int N_) {
  __shared__ int cntl[256];
  __shared__ int scn[256];
  __shared__ int cur[256];
  __shared__ float dinvl[256];
  __shared__ int sbuf[BCAP];
  __shared__ int sbase;
  const int b = blockIdx.x;
  const int tid = threadIdx.x;
  const int m = bcur[b];
  const int* srcp = bucketbuf + (size_t)b * BCAP;
  cntl[tid] = 0;
  __syncthreads();
  for (int i = tid; i < m; i += 256) atomicAdd(&cntl[(unsigned)srcp[i] >> 24], 1);
  __syncthreads();
  if (tid == 0) sbase = atomicAdd(gcursor, m);
  const int cnt = cntl[tid];
  scn[tid] = cnt;
  __syncthreads();
  for (int off = 1; off < 256; off <<= 1) {
    int u = (tid >= off) ? scn[tid - off] : 0;
    __syncthreads();
    scn[tid] += u;
    __syncthreads();
  }
  const int excl = scn[tid] - cnt;
  cur[tid] = excl;
  const int base = sbase;
  const int node = (b << 8) + tid;
  const float dn = rsqrtf((float)cnt + 1.0f);
  dinvl[tid] = dn;
  if (node < N_) {
    rbeg[node] = base + excl;
    rend[node] = base + excl + cnt;
    dinv[node] = dn;
  }
  __syncthreads();
  for (int i = tid; i < m; i += 256) {
    const int v = srcp[i];
    const int slot = atomicAdd(&cur[(unsigned)v >> 24], 1);
    sbuf[slot] = v & 0xFFFFFF;
  }
  __syncthreads();
  for (int i = tid; i < m; i += 256) edata[(size_t)base + i] = sbuf[i];
  const int nb0 = b << 8;
  for (int i = tid; i < 1024; i += 256) {
    const int nd = nb0 + (i >> 2);
    if (nd < N_) {
      const float d2 = dinvl[i >> 2];
      const float2 v2 = reinterpret_cast<const float2*>(x)[(size_t)nd * 4 + (i & 3)];
      xs[(size_t)nd * 4 + (i & 3)] = __floats2half2_rn(v2.x * d2, v2.y * d2);
    }
  }
}

// ============ l12: gather(xs) + mm1 + BN1 + ReLU + mm2 + dinv, fully fused ============
__global__ void l12(const __half* __restrict__ xs, const float* __restrict__ dinv,
                    const int* __restrict__ rbeg, const int* __restrict__ rend,
                    const int* __restrict__ edata, const float* __restrict__ W1,
                    const float* __restrict__ W2, const float* __restrict__ bn,
                    __half* __restrict__ h2, int n) {
  __shared__ float shw1[8 * 64];
  __shared__ float shagg[32][8];
  __shared__ __half2 sht1[32 * 33];
  __shared__ uint4 shw2[32 * 16];
  const int tid = threadIdx.x;
  const int node0 = blockIdx.x * 32;
  for (int i = tid; i < 512; i += 256) shw1[i] = W1[i];
  {
    __half2* shw2h = reinterpret_cast<__half2*>(shw2);
    for (int i = tid; i < 32 * 64; i += 256) {
      const int kp = i >> 6, c = i & 63;
      shw2h[kp * 64 + c] = __floats2half2_rn(W2[(2 * kp) * 64 + c], W2[(2 * kp + 1) * 64 + c]);
    }
  }
  const int lane = tid & 63;
  const int nl = ((tid >> 6) << 3) + (lane >> 3);
  const int grp = lane & 7;
  const int node = node0 + nl;
  if (node < n) {
    const int beg = rbeg[node], end = rend[node];
    const uint4* xv = reinterpret_cast<const uint4*>(xs);
    __half2 c0 = __half2{0, 0}, c1 = c0, c2 = c0, c3 = c0;
    int e = beg + grp;
    for (; e + 8 < end; e += 16) {
      const uint4 q0 = xv[edata[e]];
      const uint4 q1 = xv[edata[e + 8]];
      c0 = __hadd2(c0, uh2(q0.x)); c1 = __hadd2(c1, uh2(q0.y));
      c2 = __hadd2(c2, uh2(q0.z)); c3 = __hadd2(c3, uh2(q0.w));
      c0 = __hadd2(c0, uh2(q1.x)); c1 = __hadd2(c1, uh2(q1.y));
      c2 = __hadd2(c2, uh2(q1.z)); c3 = __hadd2(c3, uh2(q1.w));
    }
    if (e < end) {
      const uint4 q = xv[edata[e]];
      c0 = __hadd2(c0, uh2(q.x)); c1 = __hadd2(c1, uh2(q.y));
      c2 = __hadd2(c2, uh2(q.z)); c3 = __hadd2(c3, uh2(q.w));
    }
#pragma unroll
    for (int m = 1; m <= 4; m <<= 1) {
      c0 = __hadd2(c0, h2shfl_xor(c0, m));
      c1 = __hadd2(c1, h2shfl_xor(c1, m));
      c2 = __hadd2(c2, h2shfl_xor(c2, m));
      c3 = __hadd2(c3, h2shfl_xor(c3, m));
    }
    if (grp == 0) {
      const uint4 q = xv[node];
      c0 = __hadd2(c0, uh2(q.x)); c1 = __hadd2(c1, uh2(q.y));
      c2 = __hadd2(c2, uh2(q.z)); c3 = __hadd2(c3, uh2(q.w));
      const float dn = dinv[node];
      const float2 f0 = h22f2(c0), f1 = h22f2(c1);
      const float2 f2 = h22f2(c2), f3 = h22f2(c3);
      shagg[nl][0] = f0.x * dn; shagg[nl][1] = f0.y * dn;
      shagg[nl][2] = f1.x * dn; shagg[nl][3] = f1.y * dn;
      shagg[nl][4] = f2.x * dn; shagg[nl][5] = f2.y * dn;
      shagg[nl][6] = f3.x * dn; shagg[nl][7] = f3.y * dn;
    }
  }
  __syncthreads();
  {
    const int mn = tid >> 3;
    const int c = (tid & 7) * 8;
    if (node0 + mn < n) {
      float a[8] = {0, 0, 0, 0, 0, 0, 0, 0};
#pragma unroll
      for (int k = 0; k < 8; ++k) {
        const float s = shagg[mn][k];
#pragma unroll
        for (int j = 0; j < 8; ++j) a[j] += s * shw1[k * 64 + c + j];
      }
      float v[8];
#pragma unroll
      for (int j = 0; j < 8; ++j) {
        float t = a[j] * bn[c + j] + bn[64 + c + j];
        v[j] = t > 0.0f ? t : 0.0f;
      }
#pragma unroll
      for (int j = 0; j < 4; ++j)
        sht1[mn * 33 + (tid & 7) * 4 + j] = __floats2half2_rn(v[2 * j], v[2 * j + 1]);
    }
  }
  __syncthreads();
  const int cq = tid & 15;
  const int nbs = (tid >> 4) * 2;
  float acc[2][4];
#pragma unroll
  for (int j = 0; j < 2; ++j)
#pragma unroll
    for (int k = 0; k < 4; ++k) acc[j][k] = 0.0f;
  for (int kp = 0; kp < 32; ++kp) {
    const uint4 wq = shw2[kp * 16 + cq];
    const float2 w0 = h22f2(uh2(wq.x)), w1 = h22f2(uh2(wq.y));
    const float2 w2 = h22f2(uh2(wq.z)), w3 = h22f2(uh2(wq.w));
#pragma unroll
    for (int j = 0; j < 2; ++j) {
      const float2 s = h22f2(sht1[(nbs + j) * 33 + kp]);
      acc[j][0] += s.x * w0.x + s.y * w0.y;
      acc[j][1] += s.x * w1.x + s.y * w1.y;
      acc[j][2] += s.x * w2.x + s.y * w2.y;
      acc[j][3] += s.x * w3.x + s.y * w3.y;
    }
  }
#pragma unroll
  for (int j = 0; j < 2; ++j) {
    const int nd = node0 + nbs + j;
    if (nd < n) {
      const float dn = dinv[nd];
      uint2 o;
      o.x = f2u(acc[j][0] * dn, acc[j][1] * dn);
      o.y = f2u(acc[j][2] * dn, acc[j][3] * dn);
      reinterpret_cast<uint2*>(h2)[(size_t)nd * 16 + cq] = o;
    }
  }
}

// ============ gh64_mm3 v2: staged gather h2' + BN2 + ReLU + mm3, 4 nodes/block ============
// Phase A: edge-parallel staged loads (zero divergence). Phase B: reduce from LDS.
__global__ void gh64_mm3(const __half* __restrict__ h, const float* __restrict__ dinv,
                         const int* __restrict__ rbeg, const int* __restrict__ rend,
                         const int* __restrict__ edata, const float* __restrict__ W3,
                         const float* __restrict__ bn, __half* __restrict__ h3, int n) {
  __shared__ int se[STG_H];             // 384 B
  __shared__ uint4 sstage[STG_H * 8];   // 12 KB: [edge][qi]
  __shared__ __half2 shagg2[4 * 33];    // post-BN2+ReLU
  __shared__ __half2 shw3[32 * 32];     // [kp][c]
  const int tid = threadIdx.x;
  const int node0 = blockIdx.x * 4;
  const int last = min(node0 + 3, n - 1);
  const int gb = rbeg[node0];
  const int total = rend[last] - gb;    // contiguous: block never crosses a bucket
  const bool lds = (total <= STG_H);
  for (int i = tid; i < 32 * 32; i += 256) {
    const int kp = i >> 5, c = i & 31;
    shw3[kp * 32 + c] = __floats2half2_rn(W3[(2 * kp) * 32 + c], W3[(2 * kp + 1) * 32 + c]);
  }
  const uint4* hv = reinterpret_cast<const uint4*>(h);
  if (lds) {
    for (int i = tid; i < total; i += 256) se[i] = edata[gb + i];
  }
  __syncthreads();
  if (lds) {
    // Phase A: balanced edge-parallel staging
    const int nslots = total * 8;
    for (int slot = tid; slot < nslots; slot += 256) {
      const int e = slot >> 3, q = slot & 7;
      sstage[slot] = hv[(size_t)se[e] * 8 + q];
    }
  }
  __syncthreads();
  // Phase B: node = wave; 8 groups x 8 qi lanes
  const int lane = tid & 63;
  const int node = node0 + (tid >> 6);
  const int qi = lane & 7;
  const int grp = lane >> 3;
  if (node < n) {
    __half2 c0 = __half2{0, 0}, c1 = c0, c2 = c0, c3 = c0;
    if (lds) {
      const int lbeg = rbeg[node] - gb, lend = rend[node] - gb;
      for (int e = lbeg + grp; e < lend; e += 8) {
        const uint4 q = sstage[e * 8 + qi];
        c0 = __hadd2(c0, uh2(q.x)); c1 = __hadd2(c1, uh2(q.y));
        c2 = __hadd2(c2, uh2(q.z)); c3 = __hadd2(c3, uh2(q.w));
      }
    } else {
      const int beg = rbeg[node], end = rend[node];
      for (int e = beg + grp; e < end; e += 8) {
        const uint4 q = hv[(size_t)edata[e] * 8 + qi];
        c0 = __hadd2(c0, uh2(q.x)); c1 = __hadd2(c1, uh2(q.y));
        c2 = __hadd2(c2, uh2(q.z)); c3 = __hadd2(c3, uh2(q.w));
      }
    }
#pragma unroll
    for (int m = 8; m <= 32; m <<= 1) {
      c0 = __hadd2(c0, h2shfl_xor(c0, m));
      c1 = __hadd2(c1, h2shfl_xor(c1, m));
      c2 = __hadd2(c2, h2shfl_xor(c2, m));
      c3 = __hadd2(c3, h2shfl_xor(c3, m));
    }
    if (grp == 0) {
      const uint4 q = hv[(size_t)node * 8 + qi];  // self term
      c0 = __hadd2(c0, uh2(q.x)); c1 = __hadd2(c1, uh2(q.y));
      c2 = __hadd2(c2, uh2(q.z)); c3 = __hadd2(c3, uh2(q.w));
      const float dn = dinv[node];
      const int nl = node - node0;
      const float2 f[4] = {h22f2(c0), h22f2(c1), h22f2(c2), h22f2(c3)};
#pragma unroll
      for (int j = 0; j < 4; ++j) {
        const int ch = qi * 8 + 2 * j;
        float v0 = f[j].x * dn * bn[128 + ch] + bn[192 + ch];
        float v1 = f[j].y * dn * bn[128 + ch + 1] + bn[192 + ch + 1];
        v0 = v0 > 0.0f ? v0 : 0.0f;
        v1 = v1 > 0.0f ? v1 : 0.0f;
        shagg2[nl * 33 + qi * 4 + j] = __floats2half2_rn(v0, v1);
      }
    }
  }
  __syncthreads();
  // mm3 phase: 128 active threads = 4 nodes x 32 channels
  if (tid < 128) {
    const int mnode = node0 + (tid >> 5);
    const int c = tid & 31;
    float acc = 0.0f;
#pragma unroll 8
    for (int kp = 0; kp < 32; ++kp) {
      const float2 s = h22f2(shagg2[(tid >> 5) * 33 + kp]);
      const float2 w = h22f2(shw3[kp * 32 + c]);
      acc += s.x * w.x + s.y * w.y;
    }
    float outv = 0.0f;
    if (mnode < n) outv = acc * dinv[mnode];
    const float partner = __shfl_xor(outv, 1);
    if ((c & 1) == 0 && mnode < n) {
      reinterpret_cast<unsigned*>(h3)[(size_t)mnode * 16 + (c >> 1)] = f2u(outv, partner);
    }
  }
}

// ============ gather_cls v2: staged gather h3' + BN3 + ReLU + classifier, 8 nodes/block ============
__global__ void gather_cls(const __half* __restrict__ h, const float* __restrict__ dinv,
                           const int* __restrict__ rbeg, const int* __restrict__ rend,
                           const int* __restrict__ edata, const float* __restrict__ bn,
                           const float* __restrict__ Wc, const float* __restrict__ bc,
                           float* __restrict__ out, int n) {
  __shared__ int se[STG_C];             // 640 B
  __shared__ uint4 sstage[STG_C * 4];   // 10 KB: [edge][qi]
  const int tid = threadIdx.x;
  const int node0 = blockIdx.x * 8;
  const int last = min(node0 + 7, n - 1);
  const int gb = rbeg[node0];
  const int total = rend[last] - gb;
  const bool lds = (total <= STG_C);
  const uint4* hv = reinterpret_cast<const uint4*>(h);
  if (lds) {
    for (int i = tid; i < total; i += 256) se[i] = edata[gb + i];
  }
  __syncthreads();
  if (lds) {
    const int nslots = total * 4;
    for (int slot = tid; slot < nslots; slot += 256) {
      const int e = slot >> 2, q = slot & 3;
      sstage[slot] = hv[(size_t)se[e] * 4 + q];
    }
  }
  __syncthreads();
  const int lane = tid & 63;
  const int node = node0 + ((tid >> 6) << 1) + (lane >> 5);
  if (node >= n) return;
  const int sub = lane & 31;
  const int qi = sub & 3;     // uint4 index within 64B row
  const int grp = sub >> 2;   // 8 groups per node
  __half2 c0 = __half2{0, 0}, c1 = c0, c2 = c0, c3 = c0;
  if (lds) {
    const int lbeg = rbeg[node] - gb, lend = rend[node] - gb;
    for (int e = lbeg + grp; e < lend; e += 8) {
      const uint4 q = sstage[e * 4 + qi];
      c0 = __hadd2(c0, uh2(q.x)); c1 = __hadd2(c1, uh2(q.y));
      c2 = __hadd2(c2, uh2(q.z)); c3 = __hadd2(c3, uh2(q.w));
    }
  } else {
    const int beg = rbeg[node], end = rend[node];
    for (int e = beg + grp; e < end; e += 8) {
      const uint4 q = hv[(size_t)edata[e] * 4 + qi];
      c0 = __hadd2(c0, uh2(q.x)); c1 = __hadd2(c1, uh2(q.y));
      c2 = __hadd2(c2, uh2(q.z)); c3 = __hadd2(c3, uh2(q.w));
    }
  }
#pragma unroll
  for (int m = 4; m <= 16; m <<= 1) {
    c0 = __hadd2(c0, h2shfl_xor(c0, m));
    c1 = __hadd2(c1, h2shfl_xor(c1, m));
    c2 = __hadd2(c2, h2shfl_xor(c2, m));
    c3 = __hadd2(c3, h2shfl_xor(c3, m));
  }
  if (grp != 0) return;
  {
    const uint4 q = hv[(size_t)node * 4 + qi];  // self term
    c0 = __hadd2(c0, uh2(q.x)); c1 = __hadd2(c1, uh2(q.y));
    c2 = __hadd2(c2, uh2(q.z)); c3 = __hadd2(c3, uh2(q.w));
  }
  const float dn = dinv[node];
  const float2 f0 = h22f2(c0), f1 = h22f2(c1);
  const float2 f2 = h22f2(c2), f3 = h22f2(c3);
  const float v[8] = {f0.x * dn, f0.y * dn, f1.x * dn, f1.y * dn,
                      f2.x * dn, f2.y * dn, f3.x * dn, f3.y * dn};
  float l0 = 0.0f, l1 = 0.0f;
#pragma unroll
  for (int j = 0; j < 8; ++j) {
    const int c = qi * 8 + j;
    float t = v[j] * bn[256 + c] + bn[288 + c];
    t = t > 0.0f ? t : 0.0f;
    const float2 w = *reinterpret_cast<const float2*>(&Wc[c * 2]);
    l0 += t * w.x;
    l1 += t * w.y;
  }
  l0 += __shfl_xor(l0, 1); l1 += __shfl_xor(l1, 1);
  l0 += __shfl_xor(l0, 2); l1 += __shfl_xor(l1, 2);
  if (qi == 0) {
    l0 += bc[0];
    l1 += bc[1];
    const float m = fmaxf(l0, l1);
    const float lse = m + log1pf(expf(-fabsf(l0 - l1)));
    *reinterpret_cast<float2*>(&out[(size_t)node * 2]) = make_float2(l0 - lse, l1 - lse);
  }
}

// ============ launch ============
extern "C" void kernel_launch(void* const* d_in, const int* in_sizes, int n_in,
                              void* d_out, int out_size, void* d_ws, size_t ws_size,
                              hipStream_t stream) {
  const float* x  = (const float*)d_in[0];
  const int* ei   = (const int*)d_in[1];   // int32 on device per harness contract
  const float* W1 = (const float*)d_in[2];
  const float* b1 = (const float*)d_in[3];
  const float* g1 = (const float*)d_in[4];
  const float* be1 = (const float*)d_in[5];
  const float* rm1 = (const float*)d_in[6];
  const float* rv1 = (const float*)d_in[7];
  const float* W2 = (const float*)d_in[8];
  const float* b2 = (const float*)d_in[9];
  const float* g2 = (const float*)d_in[10];
  const float* be2 = (const float*)d_in[11];
  const float* rm2 = (const float*)d_in[12];
  const float* rv2 = (const float*)d_in[13];
  const float* W3 = (const float*)d_in[14];
  const float* b3 = (const float*)d_in[15];
  const float* g3 = (const float*)d_in[16];
  const float* be3 = (const float*)d_in[17];
  const float* rm3 = (const float*)d_in[18];
  const float* rv3 = (const float*)d_in[19];
  const float* Wc = (const float*)d_in[20];
  const float* bc = (const float*)d_in[21];

  const int N_ = in_sizes[0] / 8;
  const int E_ = in_sizes[1] / 2;
  const int NB = (N_ + 255) >> 8;

  auto align = [](size_t v) { return (v + 255) & ~(size_t)255; };
  char* ws = (char*)d_ws;
  size_t off = 0;
  float* dinv   = (float*)(ws + off); off += align((size_t)N_ * 4);
  int* bcur     = (int*)(ws + off);   off += align(((size_t)NB + 1) * 4);
  int* rbeg     = (int*)(ws + off);   off += align((size_t)N_ * 4);
  int* rend     = (int*)(ws + off);   off += align((size_t)N_ * 4);
  float* bnbuf  = (float*)(ws + off); off += align(320 * 4);
  int* edata    = (int*)(ws + off);   off += align((size_t)E_ * 4);
  __half* xs    = (__half*)(ws + off); off += align((size_t)N_ * 8 * 2);
  char* regionA = ws + off;           off += align((size_t)NB * BCAP * 4);
  char* regionB = ws + off;           off += align((size_t)N_ * 64 * 2);

  int* bucketbuf = (int*)regionA;
  __half* h3   = (__half*)regionA;   // after p2_sort consumed bucketbuf
  __half* h2   = (__half*)regionB;
  int* gcursor = bcur + NB;

  prep<<<1 + (NB + 1 + 255) / 256, 256, 0, stream>>>(b1, g1, be1, rm1, rv1,
                                                     b2, g2, be2, rm2, rv2,
                                                     b3, g3, be3, rm3, rv3, bnbuf, bcur, NB);
  p1_partition<<<(E_ + 4095) / 4096, 256, 0, stream>>>(ei, bucketbuf, bcur, E_, NB);
  p2_sort<<<NB, 256, 0, stream>>>(bucketbuf, bcur, gcursor, edata, rbeg, rend,
                                  dinv, x, (__half2*)xs, N_);

  l12<<<(N_ + 31) / 32, 256, 0, stream>>>(xs, dinv, rbeg, rend, edata, W1, W2, bnbuf, h2, N_);

  gh64_mm3<<<(N_ + 3) / 4, 256, 0, stream>>>(h2, dinv, rbeg, rend, edata, W3, bnbuf, h3, N_);

  gather_cls<<<(N_ + 7) / 8, 256, 0, stream>>>(h3, dinv, rbeg, rend, edata,
                                               bnbuf, Wc, bc, (float*)d_out, N_);
}

// Round 15
// 147.507 us; speedup vs baseline: 1.2685x; 1.2685x over previous
//
#include <hip/hip_runtime.h>
#include <hip/hip_fp16.h>

#define BN_EPS 1e-5f
#define BCAP 5120        // bucket capacity (mean 4096 edges/bucket)
#define EDCAP_H64 640    // LDS edge staging, gh64_mm3: 16 nodes/block (mean 256, +24sigma)
#define EDCAP_CLS 1280   // LDS edge staging, gather_cls: 16 nodes/block (mean 256)

__device__ __forceinline__ unsigned f2u(float a, float b) {
  __half2 h = __floats2half2_rn(a, b);
  return *reinterpret_cast<unsigned*>(&h);
}
__device__ __forceinline__ __half2 uh2(unsigned u) {
  return *reinterpret_cast<__half2*>(&u);
}
__device__ __forceinline__ float2 h22f2(__half2 h) { return __half22float2(h); }
__device__ __forceinline__ __half2 h2shfl_xor(__half2 v, int m) {
  int i = *reinterpret_cast<int*>(&v);
  i = __shfl_xor(i, m);
  return *reinterpret_cast<__half2*>(&i);
}

// ============ prep: block 0 computes BN constants; other blocks zero bcur[0..NB] ============
// bn layout: sc1[64] | sh1[64] | sc2[64] | sh2[64] | sc3[32] | sh3[32]
__global__ void prep(const float* __restrict__ b1, const float* __restrict__ g1,
                     const float* __restrict__ be1, const float* __restrict__ rm1,
                     const float* __restrict__ rv1,
                     const float* __restrict__ b2, const float* __restrict__ g2,
                     const float* __restrict__ be2, const float* __restrict__ rm2,
                     const float* __restrict__ rv2,
                     const float* __restrict__ b3, const float* __restrict__ g3,
                     const float* __restrict__ be3, const float* __restrict__ rm3,
                     const float* __restrict__ rv3,
                     float* __restrict__ bn, int* __restrict__ bcur, int NB) {
  if (blockIdx.x == 0) {
    const int t = threadIdx.x;
    if (t < 64) {
      const float s = g1[t] * rsqrtf(rv1[t] + BN_EPS);
      bn[t] = s;
      bn[64 + t] = (b1[t] - rm1[t]) * s + be1[t];
    } else if (t < 128) {
      const int c = t - 64;
      const float s = g2[c] * rsqrtf(rv2[c] + BN_EPS);
      bn[128 + c] = s;
      bn[192 + c] = (b2[c] - rm2[c]) * s + be2[c];
    } else if (t < 160) {
      const int c = t - 128;
      const float s = g3[c] * rsqrtf(rv3[c] + BN_EPS);
      bn[256 + c] = s;
      bn[288 + c] = (b3[c] - rm3[c]) * s + be3[c];
    }
  } else {
    const int i = (blockIdx.x - 1) * 256 + threadIdx.x;
    if (i <= NB) bcur[i] = 0;  // includes the global cursor at bcur[NB]
  }
}

// ============ Phase 1: partition edges into per-bucket regions (bucket = dst>>8) ============
__global__ void p1_partition(const int* __restrict__ ei, int* __restrict__ bucketbuf,
                             int* __restrict__ bcur, int E_, int NB) {
  __shared__ int pk[4096];
  __shared__ short bk[4096];
  __shared__ int hist[512];
  __shared__ int bbase[512];
  const int tid = threadIdx.x;
  const int e0 = blockIdx.x * 4096;
  const int ecount = min(4096, E_ - e0);
  for (int i = tid; i < NB; i += 256) hist[i] = 0;
  __syncthreads();
  for (int i = tid; i < ecount; i += 256) {
    const int s = ei[e0 + i];
    const int d = ei[(size_t)E_ + e0 + i];
    pk[i] = ((d & 255) << 24) | s;   // src < 2^24 (N = 100000)
    const int b = d >> 8;
    bk[i] = (short)b;
    atomicAdd(&hist[b], 1);
  }
  __syncthreads();
  for (int i = tid; i < NB; i += 256) {
    const int c = hist[i];
    bbase[i] = c ? atomicAdd(&bcur[i], c) : 0;
    hist[i] = 0;  // reuse as local cursor
  }
  __syncthreads();
  for (int i = tid; i < ecount; i += 256) {
    const int b = bk[i];
    const int slot = bbase[b] + atomicAdd(&hist[b], 1);
    bucketbuf[(size_t)b * BCAP + slot] = pk[i];
  }
}

// ============ Phase 2: per-bucket counting sort; atomic global base; emits rbeg/rend, dinv, xs ============
__global__ void p2_sort(const int* __restrict__ bucketbuf, const int* __restrict__ bcur,
                        int* __restrict__ gcursor, int* __restrict__ edata,
                        int* __restrict__ rbeg, int* __restrict__ rend,
                        float* __restrict__ dinv, const float* __restrict__ x,
                        __half2* __restrict__ xs, int N_) {
  __shared__ int cntl[256];
  __shared__ int scn[256];
  __shared__ int cur[256];
  __shared__ float dinvl[256];
  __shared__ int sbuf[BCAP];
  __shared__ int sbase;
  const int b = blockIdx.x;
  const int tid = threadIdx.x;
  const int m = bcur[b];
  const int* srcp = bucketbuf + (size_t)b * BCAP;
  cntl[tid] = 0;
  __syncthreads();
  for (int i = tid; i < m; i += 256) atomicAdd(&cntl[(unsigned)srcp[i] >> 24], 1);
  __syncthreads();
  if (tid == 0) sbase = atomicAdd(gcursor, m);  // order-free range claim
  const int cnt = cntl[tid];
  scn[tid] = cnt;
  __syncthreads();
  for (int off = 1; off < 256; off <<= 1) {
    int u = (tid >= off) ? scn[tid - off] : 0;
    __syncthreads();
    scn[tid] += u;
    __syncthreads();
  }
  const int excl = scn[tid] - cnt;
  cur[tid] = excl;
  const int base = sbase;  // barriers in scan loop make this visible
  const int node = (b << 8) + tid;
  const float dn = rsqrtf((float)cnt + 1.0f);  // deg = in-degree + self-loop
  dinvl[tid] = dn;
  if (node < N_) {
    rbeg[node] = base + excl;
    rend[node] = base + excl + cnt;
    dinv[node] = dn;
  }
  __syncthreads();
  for (int i = tid; i < m; i += 256) {
    const int v = srcp[i];
    const int slot = atomicAdd(&cur[(unsigned)v >> 24], 1);
    sbuf[slot] = v & 0xFFFFFF;
  }
  __syncthreads();
  for (int i = tid; i < m; i += 256) edata[(size_t)base + i] = sbuf[i];
  // fused: xs = fp16(dinv * x) for this bucket's 256 nodes (coalesced x reads)
  const int nb0 = b << 8;
  for (int i = tid; i < 1024; i += 256) {
    const int nd = nb0 + (i >> 2);
    if (nd < N_) {
      const float d2 = dinvl[i >> 2];
      const float2 v2 = reinterpret_cast<const float2*>(x)[(size_t)nd * 4 + (i & 3)];
      xs[(size_t)nd * 4 + (i & 3)] = __floats2half2_rn(v2.x * d2, v2.y * d2);
    }
  }
}

// ============ l12: gather(xs) + mm1 + BN1 + ReLU + mm2 + dinv, fully fused ============
// Block = 256 threads = 32 nodes. t1 lives only in LDS.
__global__ void l12(const __half* __restrict__ xs, const float* __restrict__ dinv,
                    const int* __restrict__ rbeg, const int* __restrict__ rend,
                    const int* __restrict__ edata, const float* __restrict__ W1,
                    const float* __restrict__ W2, const float* __restrict__ bn,
                    __half* __restrict__ h2, int n) {
  __shared__ float shw1[8 * 64];
  __shared__ float shagg[32][8];
  __shared__ __half2 sht1[32 * 33];
  __shared__ uint4 shw2[32 * 16];
  const int tid = threadIdx.x;
  const int node0 = blockIdx.x * 32;
  for (int i = tid; i < 512; i += 256) shw1[i] = W1[i];
  {
    __half2* shw2h = reinterpret_cast<__half2*>(shw2);
    for (int i = tid; i < 32 * 64; i += 256) {
      const int kp = i >> 6, c = i & 63;
      shw2h[kp * 64 + c] = __floats2half2_rn(W2[(2 * kp) * 64 + c], W2[(2 * kp + 1) * 64 + c]);
    }
  }
  const int lane = tid & 63;
  const int nl = ((tid >> 6) << 3) + (lane >> 3);
  const int grp = lane & 7;
  const int node = node0 + nl;
  if (node < n) {
    const int beg = rbeg[node], end = rend[node];
    const uint4* xv = reinterpret_cast<const uint4*>(xs);
    __half2 c0 = __half2{0, 0}, c1 = c0, c2 = c0, c3 = c0;
    int e = beg + grp;
    for (; e + 8 < end; e += 16) {
      const uint4 q0 = xv[edata[e]];
      const uint4 q1 = xv[edata[e + 8]];
      c0 = __hadd2(c0, uh2(q0.x)); c1 = __hadd2(c1, uh2(q0.y));
      c2 = __hadd2(c2, uh2(q0.z)); c3 = __hadd2(c3, uh2(q0.w));
      c0 = __hadd2(c0, uh2(q1.x)); c1 = __hadd2(c1, uh2(q1.y));
      c2 = __hadd2(c2, uh2(q1.z)); c3 = __hadd2(c3, uh2(q1.w));
    }
    if (e < end) {
      const uint4 q = xv[edata[e]];
      c0 = __hadd2(c0, uh2(q.x)); c1 = __hadd2(c1, uh2(q.y));
      c2 = __hadd2(c2, uh2(q.z)); c3 = __hadd2(c3, uh2(q.w));
    }
#pragma unroll
    for (int m = 1; m <= 4; m <<= 1) {
      c0 = __hadd2(c0, h2shfl_xor(c0, m));
      c1 = __hadd2(c1, h2shfl_xor(c1, m));
      c2 = __hadd2(c2, h2shfl_xor(c2, m));
      c3 = __hadd2(c3, h2shfl_xor(c3, m));
    }
    if (grp == 0) {
      const uint4 q = xv[node];
      c0 = __hadd2(c0, uh2(q.x)); c1 = __hadd2(c1, uh2(q.y));
      c2 = __hadd2(c2, uh2(q.z)); c3 = __hadd2(c3, uh2(q.w));
      const float dn = dinv[node];
      const float2 f0 = h22f2(c0), f1 = h22f2(c1);
      const float2 f2 = h22f2(c2), f3 = h22f2(c3);
      shagg[nl][0] = f0.x * dn; shagg[nl][1] = f0.y * dn;
      shagg[nl][2] = f1.x * dn; shagg[nl][3] = f1.y * dn;
      shagg[nl][4] = f2.x * dn; shagg[nl][5] = f2.y * dn;
      shagg[nl][6] = f3.x * dn; shagg[nl][7] = f3.y * dn;
    }
  }
  __syncthreads();
  {
    const int mn = tid >> 3;
    const int c = (tid & 7) * 8;
    if (node0 + mn < n) {
      float a[8] = {0, 0, 0, 0, 0, 0, 0, 0};
#pragma unroll
      for (int k = 0; k < 8; ++k) {
        const float s = shagg[mn][k];
#pragma unroll
        for (int j = 0; j < 8; ++j) a[j] += s * shw1[k * 64 + c + j];
      }
      float v[8];
#pragma unroll
      for (int j = 0; j < 8; ++j) {
        float t = a[j] * bn[c + j] + bn[64 + c + j];
        v[j] = t > 0.0f ? t : 0.0f;
      }
#pragma unroll
      for (int j = 0; j < 4; ++j)
        sht1[mn * 33 + (tid & 7) * 4 + j] = __floats2half2_rn(v[2 * j], v[2 * j + 1]);
    }
  }
  __syncthreads();
  const int cq = tid & 15;
  const int nbs = (tid >> 4) * 2;
  float acc[2][4];
#pragma unroll
  for (int j = 0; j < 2; ++j)
#pragma unroll
    for (int k = 0; k < 4; ++k) acc[j][k] = 0.0f;
  for (int kp = 0; kp < 32; ++kp) {
    const uint4 wq = shw2[kp * 16 + cq];
    const float2 w0 = h22f2(uh2(wq.x)), w1 = h22f2(uh2(wq.y));
    const float2 w2 = h22f2(uh2(wq.z)), w3 = h22f2(uh2(wq.w));
#pragma unroll
    for (int j = 0; j < 2; ++j) {
      const float2 s = h22f2(sht1[(nbs + j) * 33 + kp]);
      acc[j][0] += s.x * w0.x + s.y * w0.y;
      acc[j][1] += s.x * w1.x + s.y * w1.y;
      acc[j][2] += s.x * w2.x + s.y * w2.y;
      acc[j][3] += s.x * w3.x + s.y * w3.y;
    }
  }
#pragma unroll
  for (int j = 0; j < 2; ++j) {
    const int nd = node0 + nbs + j;
    if (nd < n) {
      const float dn = dinv[nd];
      uint2 o;
      o.x = f2u(acc[j][0] * dn, acc[j][1] * dn);
      o.y = f2u(acc[j][2] * dn, acc[j][3] * dn);
      reinterpret_cast<uint2*>(h2)[(size_t)nd * 16 + cq] = o;
    }
  }
}

// ============ gh64_mm3: gather h2' + dinv + BN2 + ReLU + mm3 + dinv, fused ============
// 16 nodes/block; 4 nodes/wave (2 groups x 8 qi-lanes); agg2 lives only in LDS.
__global__ void gh64_mm3(const __half* __restrict__ h, const float* __restrict__ dinv,
                         const int* __restrict__ rbeg, const int* __restrict__ rend,
                         const int* __restrict__ edata, const float* __restrict__ W3,
                         const float* __restrict__ bn, __half* __restrict__ h3, int n) {
  __shared__ int se[EDCAP_H64];        // 2.5 KB
  __shared__ __half2 shagg2[16 * 33];  // 2.1 KB (post-BN2+ReLU)
  __shared__ __half2 shw3[32 * 32];    // 4 KB [kp][c]
  __shared__ float shbn[128];          // sc2|sh2
  const int tid = threadIdx.x;
  const int node0 = blockIdx.x * 16;
  const int last = min(node0 + 15, n - 1);
  const int gb = rbeg[node0];
  const int total = rend[last] - gb;   // block's nodes are contiguous in edata (same bucket)
  const bool lds = (total <= EDCAP_H64);
  if (lds) {
    for (int i = tid; i < total; i += 256) se[i] = edata[gb + i];
  }
  for (int i = tid; i < 32 * 32; i += 256) {
    const int kp = i >> 5, c = i & 31;
    shw3[kp * 32 + c] = __floats2half2_rn(W3[(2 * kp) * 32 + c], W3[(2 * kp + 1) * 32 + c]);
  }
  if (tid < 128) shbn[tid] = bn[128 + tid];
  __syncthreads();
  // ---- gather phase: 4 nodes/wave; per node 2 groups x 8 qi-lanes; unroll-4 ----
  const int lane = tid & 63;
  const int node = node0 + ((tid >> 6) << 2) + (lane >> 4);
  const int sub = lane & 15;
  const int qi = sub & 7;     // uint4 index within 128B row
  const int grp = sub >> 3;   // 2 groups per node
  if (node < n) {
    const uint4* hv = reinterpret_cast<const uint4*>(h);
    __half2 c0 = __half2{0, 0}, c1 = c0, c2 = c0, c3 = c0;
    if (lds) {
      const int lbeg = rbeg[node] - gb, lend = rend[node] - gb;
      int e = lbeg + grp;
      for (; e + 6 < lend; e += 8) {
        const int s0 = se[e], s1 = se[e + 2], s2 = se[e + 4], s3 = se[e + 6];
        const uint4 q0 = hv[(size_t)s0 * 8 + qi];
        const uint4 q1 = hv[(size_t)s1 * 8 + qi];
        const uint4 q2 = hv[(size_t)s2 * 8 + qi];
        const uint4 q3 = hv[(size_t)s3 * 8 + qi];
        c0 = __hadd2(c0, uh2(q0.x)); c1 = __hadd2(c1, uh2(q0.y));
        c2 = __hadd2(c2, uh2(q0.z)); c3 = __hadd2(c3, uh2(q0.w));
        c0 = __hadd2(c0, uh2(q1.x)); c1 = __hadd2(c1, uh2(q1.y));
        c2 = __hadd2(c2, uh2(q1.z)); c3 = __hadd2(c3, uh2(q1.w));
        c0 = __hadd2(c0, uh2(q2.x)); c1 = __hadd2(c1, uh2(q2.y));
        c2 = __hadd2(c2, uh2(q2.z)); c3 = __hadd2(c3, uh2(q2.w));
        c0 = __hadd2(c0, uh2(q3.x)); c1 = __hadd2(c1, uh2(q3.y));
        c2 = __hadd2(c2, uh2(q3.z)); c3 = __hadd2(c3, uh2(q3.w));
      }
      for (; e < lend; e += 2) {
        const uint4 q = hv[(size_t)se[e] * 8 + qi];
        c0 = __hadd2(c0, uh2(q.x)); c1 = __hadd2(c1, uh2(q.y));
        c2 = __hadd2(c2, uh2(q.z)); c3 = __hadd2(c3, uh2(q.w));
      }
    } else {
      const int beg = rbeg[node], end = rend[node];
      for (int e = beg + grp; e < end; e += 2) {
        const uint4 q = hv[(size_t)edata[e] * 8 + qi];
        c0 = __hadd2(c0, uh2(q.x)); c1 = __hadd2(c1, uh2(q.y));
        c2 = __hadd2(c2, uh2(q.z)); c3 = __hadd2(c3, uh2(q.w));
      }
    }
    // reduce across 2 groups (lane bit 3)
    c0 = __hadd2(c0, h2shfl_xor(c0, 8));
    c1 = __hadd2(c1, h2shfl_xor(c1, 8));
    c2 = __hadd2(c2, h2shfl_xor(c2, 8));
    c3 = __hadd2(c3, h2shfl_xor(c3, 8));
    if (grp == 0) {
      const uint4 q = hv[(size_t)node * 8 + qi];  // self term
      c0 = __hadd2(c0, uh2(q.x)); c1 = __hadd2(c1, uh2(q.y));
      c2 = __hadd2(c2, uh2(q.z)); c3 = __hadd2(c3, uh2(q.w));
      const float dn = dinv[node];
      const int nl = node - node0;
      const float2 f[4] = {h22f2(c0), h22f2(c1), h22f2(c2), h22f2(c3)};
#pragma unroll
      for (int j = 0; j < 4; ++j) {
        const int ch = qi * 8 + 2 * j;
        float v0 = f[j].x * dn * shbn[ch] + shbn[64 + ch];
        float v1 = f[j].y * dn * shbn[ch + 1] + shbn[64 + ch + 1];
        v0 = v0 > 0.0f ? v0 : 0.0f;
        v1 = v1 > 0.0f ? v1 : 0.0f;
        shagg2[nl * 33 + qi * 4 + j] = __floats2half2_rn(v0, v1);
      }
    }
  }
  __syncthreads();
  // ---- mm3 phase: all 256 threads; each handles 2 nodes (nl, nl+8) x 1 channel ----
  const int c = tid & 31;
#pragma unroll
  for (int j = 0; j < 2; ++j) {
    const int nl = (tid >> 5) + 8 * j;
    const int mnode = node0 + nl;
    float acc = 0.0f;
#pragma unroll 8
    for (int kp = 0; kp < 32; ++kp) {
      const float2 s = h22f2(shagg2[nl * 33 + kp]);
      const float2 w = h22f2(shw3[kp * 32 + c]);
      acc += s.x * w.x + s.y * w.y;
    }
    float outv = 0.0f;
    if (mnode < n) outv = acc * dinv[mnode];
    const float partner = __shfl_xor(outv, 1);
    if ((c & 1) == 0 && mnode < n) {
      reinterpret_cast<unsigned*>(h3)[(size_t)mnode * 16 + (c >> 1)] = f2u(outv, partner);
    }
  }
}

// ============ gather h3' (C=32) + BN3 + ReLU + 32x2 linear + log_softmax ============
__global__ void gather_cls(const __half* __restrict__ h, const float* __restrict__ dinv,
                           const int* __restrict__ rbeg, const int* __restrict__ rend,
                           const int* __restrict__ edata, const float* __restrict__ bn,
                           const float* __restrict__ Wc, const float* __restrict__ bc,
                           float* __restrict__ out, int n) {
  __shared__ int se[EDCAP_CLS];
  const int tid = threadIdx.x;
  const int node0 = blockIdx.x * 16;
  const int last = min(node0 + 15, n - 1);
  const int gb = rbeg[node0];
  const int total = rend[last] - gb;
  const bool lds = (total <= EDCAP_CLS);
  if (lds) {
    for (int i = tid; i < total; i += 256) se[i] = edata[gb + i];
  }
  __syncthreads();
  const int lane = tid & 63;
  const int node = node0 + ((tid >> 6) << 2) + (lane >> 4);
  if (node >= n) return;
  const int qi = lane & 3;
  const int grp = (lane >> 2) & 3;
  const uint4* hv = reinterpret_cast<const uint4*>(h);
  __half2 c0 = __half2{0, 0}, c1 = c0, c2 = c0, c3 = c0;
  if (lds) {
    const int beg = rbeg[node] - gb, end = rend[node] - gb;
    int e = beg + grp;
    for (; e + 12 < end; e += 16) {
      const int s0 = se[e], s1 = se[e + 4], s2 = se[e + 8], s3 = se[e + 12];
      const uint4 q0 = hv[(size_t)s0 * 4 + qi];
      const uint4 q1 = hv[(size_t)s1 * 4 + qi];
      const uint4 q2 = hv[(size_t)s2 * 4 + qi];
      const uint4 q3 = hv[(size_t)s3 * 4 + qi];
      c0 = __hadd2(c0, uh2(q0.x)); c1 = __hadd2(c1, uh2(q0.y));
      c2 = __hadd2(c2, uh2(q0.z)); c3 = __hadd2(c3, uh2(q0.w));
      c0 = __hadd2(c0, uh2(q1.x)); c1 = __hadd2(c1, uh2(q1.y));
      c2 = __hadd2(c2, uh2(q1.z)); c3 = __hadd2(c3, uh2(q1.w));
      c0 = __hadd2(c0, uh2(q2.x)); c1 = __hadd2(c1, uh2(q2.y));
      c2 = __hadd2(c2, uh2(q2.z)); c3 = __hadd2(c3, uh2(q2.w));
      c0 = __hadd2(c0, uh2(q3.x)); c1 = __hadd2(c1, uh2(q3.y));
      c2 = __hadd2(c2, uh2(q3.z)); c3 = __hadd2(c3, uh2(q3.w));
    }
    for (; e < end; e += 4) {
      const uint4 q = hv[(size_t)se[e] * 4 + qi];
      c0 = __hadd2(c0, uh2(q.x)); c1 = __hadd2(c1, uh2(q.y));
      c2 = __hadd2(c2, uh2(q.z)); c3 = __hadd2(c3, uh2(q.w));
    }
  } else {
    const int beg = rbeg[node], end = rend[node];
    int e = beg + grp;
    for (; e + 12 < end; e += 16) {
      const int s0 = edata[e], s1 = edata[e + 4], s2 = edata[e + 8], s3 = edata[e + 12];
      const uint4 q0 = hv[(size_t)s0 * 4 + qi];
      const uint4 q1 = hv[(size_t)s1 * 4 + qi];
      const uint4 q2 = hv[(size_t)s2 * 4 + qi];
      const uint4 q3 = hv[(size_t)s3 * 4 + qi];
      c0 = __hadd2(c0, uh2(q0.x)); c1 = __hadd2(c1, uh2(q0.y));
      c2 = __hadd2(c2, uh2(q0.z)); c3 = __hadd2(c3, uh2(q0.w));
      c0 = __hadd2(c0, uh2(q1.x)); c1 = __hadd2(c1, uh2(q1.y));
      c2 = __hadd2(c2, uh2(q1.z)); c3 = __hadd2(c3, uh2(q1.w));
      c0 = __hadd2(c0, uh2(q2.x)); c1 = __hadd2(c1, uh2(q2.y));
      c2 = __hadd2(c2, uh2(q2.z)); c3 = __hadd2(c3, uh2(q2.w));
      c0 = __hadd2(c0, uh2(q3.x)); c1 = __hadd2(c1, uh2(q3.y));
      c2 = __hadd2(c2, uh2(q3.z)); c3 = __hadd2(c3, uh2(q3.w));
    }
    for (; e < end; e += 4) {
      const uint4 q = hv[(size_t)edata[e] * 4 + qi];
      c0 = __hadd2(c0, uh2(q.x)); c1 = __hadd2(c1, uh2(q.y));
      c2 = __hadd2(c2, uh2(q.z)); c3 = __hadd2(c3, uh2(q.w));
    }
  }
#pragma unroll
  for (int m = 4; m <= 8; m <<= 1) {
    c0 = __hadd2(c0, h2shfl_xor(c0, m));
    c1 = __hadd2(c1, h2shfl_xor(c1, m));
    c2 = __hadd2(c2, h2shfl_xor(c2, m));
    c3 = __hadd2(c3, h2shfl_xor(c3, m));
  }
  if (grp != 0) return;
  // self term
  {
    const uint4 q = hv[(size_t)node * 4 + qi];
    c0 = __hadd2(c0, uh2(q.x)); c1 = __hadd2(c1, uh2(q.y));
    c2 = __hadd2(c2, uh2(q.z)); c3 = __hadd2(c3, uh2(q.w));
  }
  const float dn = dinv[node];
  const float2 f0 = h22f2(c0), f1 = h22f2(c1);
  const float2 f2 = h22f2(c2), f3 = h22f2(c3);
  const float v[8] = {f0.x * dn, f0.y * dn, f1.x * dn, f1.y * dn,
                      f2.x * dn, f2.y * dn, f3.x * dn, f3.y * dn};
  float l0 = 0.0f, l1 = 0.0f;
#pragma unroll
  for (int j = 0; j < 8; ++j) {
    const int c = qi * 8 + j;
    float t = v[j] * bn[256 + c] + bn[288 + c];
    t = t > 0.0f ? t : 0.0f;
    const float2 w = *reinterpret_cast<const float2*>(&Wc[c * 2]);
    l0 += t * w.x;
    l1 += t * w.y;
  }
  l0 += __shfl_xor(l0, 1); l1 += __shfl_xor(l1, 1);
  l0 += __shfl_xor(l0, 2); l1 += __shfl_xor(l1, 2);
  if (qi == 0) {
    l0 += bc[0];
    l1 += bc[1];
    const float m = fmaxf(l0, l1);
    const float lse = m + log1pf(expf(-fabsf(l0 - l1)));
    *reinterpret_cast<float2*>(&out[(size_t)node * 2]) = make_float2(l0 - lse, l1 - lse);
  }
}

// ============ launch ============
extern "C" void kernel_launch(void* const* d_in, const int* in_sizes, int n_in,
                              void* d_out, int out_size, void* d_ws, size_t ws_size,
                              hipStream_t stream) {
  const float* x  = (const float*)d_in[0];
  const int* ei   = (const int*)d_in[1];   // int32 on device per harness contract
  const float* W1 = (const float*)d_in[2];
  const float* b1 = (const float*)d_in[3];
  const float* g1 = (const float*)d_in[4];
  const float* be1 = (const float*)d_in[5];
  const float* rm1 = (const float*)d_in[6];
  const float* rv1 = (const float*)d_in[7];
  const float* W2 = (const float*)d_in[8];
  const float* b2 = (const float*)d_in[9];
  const float* g2 = (const float*)d_in[10];
  const float* be2 = (const float*)d_in[11];
  const float* rm2 = (const float*)d_in[12];
  const float* rv2 = (const float*)d_in[13];
  const float* W3 = (const float*)d_in[14];
  const float* b3 = (const float*)d_in[15];
  const float* g3 = (const float*)d_in[16];
  const float* be3 = (const float*)d_in[17];
  const float* rm3 = (const float*)d_in[18];
  const float* rv3 = (const float*)d_in[19];
  const float* Wc = (const float*)d_in[20];
  const float* bc = (const float*)d_in[21];

  const int N_ = in_sizes[0] / 8;
  const int E_ = in_sizes[1] / 2;
  const int NB = (N_ + 255) >> 8;

  auto align = [](size_t v) { return (v + 255) & ~(size_t)255; };
  char* ws = (char*)d_ws;
  size_t off = 0;
  float* dinv   = (float*)(ws + off); off += align((size_t)N_ * 4);
  int* bcur     = (int*)(ws + off);   off += align(((size_t)NB + 1) * 4);
  int* rbeg     = (int*)(ws + off);   off += align((size_t)N_ * 4);
  int* rend     = (int*)(ws + off);   off += align((size_t)N_ * 4);
  float* bnbuf  = (float*)(ws + off); off += align(320 * 4);
  int* edata    = (int*)(ws + off);   off += align((size_t)E_ * 4);
  __half* xs    = (__half*)(ws + off); off += align((size_t)N_ * 8 * 2);
  char* regionA = ws + off;           off += align((size_t)NB * BCAP * 4);
  char* regionB = ws + off;           off += align((size_t)N_ * 64 * 2);

  int* bucketbuf = (int*)regionA;
  __half* h3   = (__half*)regionA;   // after p2_sort consumed bucketbuf
  __half* h2   = (__half*)regionB;
  int* gcursor = bcur + NB;

  prep<<<1 + (NB + 1 + 255) / 256, 256, 0, stream>>>(b1, g1, be1, rm1, rv1,
                                                     b2, g2, be2, rm2, rv2,
                                                     b3, g3, be3, rm3, rv3, bnbuf, bcur, NB);
  p1_partition<<<(E_ + 4095) / 4096, 256, 0, stream>>>(ei, bucketbuf, bcur, E_, NB);
  p2_sort<<<NB, 256, 0, stream>>>(bucketbuf, bcur, gcursor, edata, rbeg, rend,
                                  dinv, x, (__half2*)xs, N_);

  l12<<<(N_ + 31) / 32, 256, 0, stream>>>(xs, dinv, rbeg, rend, edata, W1, W2, bnbuf, h2, N_);

  gh64_mm3<<<(N_ + 15) / 16, 256, 0, stream>>>(h2, dinv, rbeg, rend, edata, W3, bnbuf, h3, N_);

  gather_cls<<<(N_ + 15) / 16, 256, 0, stream>>>(h3, dinv, rbeg, rend, edata,
                                                 bnbuf, Wc, bc, (float*)d_out, N_);
}

// Round 16
// 147.184 us; speedup vs baseline: 1.2713x; 1.0022x over previous
//
#include <hip/hip_runtime.h>
#include <hip/hip_fp16.h>

#define BN_EPS 1e-5f
#define BCAP 5120        // bucket capacity (mean 4096 edges/bucket)
#define EDCAP_H64 640    // LDS edge staging, gh64_mm3: 16 nodes/block (mean 256)
#define EDCAP_CLS 1280   // LDS edge staging, gather_cls: 16 nodes/block (mean 256)

__device__ __forceinline__ unsigned f2u(float a, float b) {
  __half2 h = __floats2half2_rn(a, b);
  return *reinterpret_cast<unsigned*>(&h);
}
__device__ __forceinline__ __half2 uh2(unsigned u) {
  return *reinterpret_cast<__half2*>(&u);
}
__device__ __forceinline__ float2 h22f2(__half2 h) { return __half22float2(h); }
__device__ __forceinline__ __half2 h2shfl_xor(__half2 v, int m) {
  int i = *reinterpret_cast<int*>(&v);
  i = __shfl_xor(i, m);
  return *reinterpret_cast<__half2*>(&i);
}

// ============ prep: block 0 computes BN constants; other blocks zero bcur[0..NB] ============
// bn layout: sc1[64] | sh1[64] | sc2[64] | sh2[64] | sc3[32] | sh3[32]
__global__ void prep(const float* __restrict__ b1, const float* __restrict__ g1,
                     const float* __restrict__ be1, const float* __restrict__ rm1,
                     const float* __restrict__ rv1,
                     const float* __restrict__ b2, const float* __restrict__ g2,
                     const float* __restrict__ be2, const float* __restrict__ rm2,
                     const float* __restrict__ rv2,
                     const float* __restrict__ b3, const float* __restrict__ g3,
                     const float* __restrict__ be3, const float* __restrict__ rm3,
                     const float* __restrict__ rv3,
                     float* __restrict__ bn, int* __restrict__ bcur, int NB) {
  if (blockIdx.x == 0) {
    const int t = threadIdx.x;
    if (t < 64) {
      const float s = g1[t] * rsqrtf(rv1[t] + BN_EPS);
      bn[t] = s;
      bn[64 + t] = (b1[t] - rm1[t]) * s + be1[t];
    } else if (t < 128) {
      const int c = t - 64;
      const float s = g2[c] * rsqrtf(rv2[c] + BN_EPS);
      bn[128 + c] = s;
      bn[192 + c] = (b2[c] - rm2[c]) * s + be2[c];
    } else if (t < 160) {
      const int c = t - 128;
      const float s = g3[c] * rsqrtf(rv3[c] + BN_EPS);
      bn[256 + c] = s;
      bn[288 + c] = (b3[c] - rm3[c]) * s + be3[c];
    }
  } else {
    const int i = (blockIdx.x - 1) * 256 + threadIdx.x;
    if (i <= NB) bcur[i] = 0;  // includes the global cursor at bcur[NB]
  }
}

// ============ Phase 1: partition edges into per-bucket regions (bucket = dst>>8) ============
__global__ void p1_partition(const int* __restrict__ ei, int* __restrict__ bucketbuf,
                             int* __restrict__ bcur, int E_, int NB) {
  __shared__ int pk[4096];
  __shared__ short bk[4096];
  __shared__ int hist[512];
  __shared__ int bbase[512];
  const int tid = threadIdx.x;
  const int e0 = blockIdx.x * 4096;
  const int ecount = min(4096, E_ - e0);
  for (int i = tid; i < NB; i += 256) hist[i] = 0;
  __syncthreads();
  for (int i = tid; i < ecount; i += 256) {
    const int s = ei[e0 + i];
    const int d = ei[(size_t)E_ + e0 + i];
    pk[i] = ((d & 255) << 24) | s;   // src < 2^24 (N = 100000)
    const int b = d >> 8;
    bk[i] = (short)b;
    atomicAdd(&hist[b], 1);
  }
  __syncthreads();
  for (int i = tid; i < NB; i += 256) {
    const int c = hist[i];
    bbase[i] = c ? atomicAdd(&bcur[i], c) : 0;
    hist[i] = 0;  // reuse as local cursor
  }
  __syncthreads();
  for (int i = tid; i < ecount; i += 256) {
    const int b = bk[i];
    const int slot = bbase[b] + atomicAdd(&hist[b], 1);
    bucketbuf[(size_t)b * BCAP + slot] = pk[i];
  }
}

// ============ Phase 2: per-bucket counting sort; atomic global base; emits rbeg/rend, dinv, xs ============
__global__ void p2_sort(const int* __restrict__ bucketbuf, const int* __restrict__ bcur,
                        int* __restrict__ gcursor, int* __restrict__ edata,
                        int* __restrict__ rbeg, int* __restrict__ rend,
                        float* __restrict__ dinv, const float* __restrict__ x,
                        __half2* __restrict__ xs, int N_) {
  __shared__ int cntl[256];
  __shared__ int scn[256];
  __shared__ int cur[256];
  __shared__ float dinvl[256];
  __shared__ int sbuf[BCAP];
  __shared__ int sbase;
  const int b = blockIdx.x;
  const int tid = threadIdx.x;
  const int m = bcur[b];
  const int* srcp = bucketbuf + (size_t)b * BCAP;
  cntl[tid] = 0;
  __syncthreads();
  for (int i = tid; i < m; i += 256) atomicAdd(&cntl[(unsigned)srcp[i] >> 24], 1);
  __syncthreads();
  if (tid == 0) sbase = atomicAdd(gcursor, m);  // order-free range claim
  const int cnt = cntl[tid];
  scn[tid] = cnt;
  __syncthreads();
  for (int off = 1; off < 256; off <<= 1) {
    int u = (tid >= off) ? scn[tid - off] : 0;
    __syncthreads();
    scn[tid] += u;
    __syncthreads();
  }
  const int excl = scn[tid] - cnt;
  cur[tid] = excl;
  const int base = sbase;  // barriers in scan loop make this visible
  const int node = (b << 8) + tid;
  const float dn = rsqrtf((float)cnt + 1.0f);  // deg = in-degree + self-loop
  dinvl[tid] = dn;
  if (node < N_) {
    rbeg[node] = base + excl;
    rend[node] = base + excl + cnt;
    dinv[node] = dn;
  }
  __syncthreads();
  for (int i = tid; i < m; i += 256) {
    const int v = srcp[i];
    const int slot = atomicAdd(&cur[(unsigned)v >> 24], 1);
    sbuf[slot] = v & 0xFFFFFF;
  }
  __syncthreads();
  for (int i = tid; i < m; i += 256) edata[(size_t)base + i] = sbuf[i];
  // fused: xs = fp16(dinv * x) for this bucket's 256 nodes (coalesced x reads)
  const int nb0 = b << 8;
  for (int i = tid; i < 1024; i += 256) {
    const int nd = nb0 + (i >> 2);
    if (nd < N_) {
      const float d2 = dinvl[i >> 2];
      const float2 v2 = reinterpret_cast<const float2*>(x)[(size_t)nd * 4 + (i & 3)];
      xs[(size_t)nd * 4 + (i & 3)] = __floats2half2_rn(v2.x * d2, v2.y * d2);
    }
  }
}

// ============ l12: gather(xs) + mm1 + BN1 + ReLU + mm2 + dinv, fully fused ============
// Block = 256 threads = 32 nodes. t1 lives only in LDS.
__global__ void l12(const __half* __restrict__ xs, const float* __restrict__ dinv,
                    const int* __restrict__ rbeg, const int* __restrict__ rend,
                    const int* __restrict__ edata, const float* __restrict__ W1,
                    const float* __restrict__ W2, const float* __restrict__ bn,
                    __half* __restrict__ h2, int n) {
  __shared__ float shw1[8 * 64];
  __shared__ float shagg[32][8];
  __shared__ __half2 sht1[32 * 33];
  __shared__ uint4 shw2[32 * 16];
  const int tid = threadIdx.x;
  const int node0 = blockIdx.x * 32;
  for (int i = tid; i < 512; i += 256) shw1[i] = W1[i];
  {
    __half2* shw2h = reinterpret_cast<__half2*>(shw2);
    for (int i = tid; i < 32 * 64; i += 256) {
      const int kp = i >> 6, c = i & 63;
      shw2h[kp * 64 + c] = __floats2half2_rn(W2[(2 * kp) * 64 + c], W2[(2 * kp + 1) * 64 + c]);
    }
  }
  const int lane = tid & 63;
  const int nl = ((tid >> 6) << 3) + (lane >> 3);
  const int grp = lane & 7;
  const int node = node0 + nl;
  if (node < n) {
    const int beg = rbeg[node], end = rend[node];
    const uint4* xv = reinterpret_cast<const uint4*>(xs);
    __half2 c0 = __half2{0, 0}, c1 = c0, c2 = c0, c3 = c0;
    int e = beg + grp;
    for (; e + 8 < end; e += 16) {
      const uint4 q0 = xv[edata[e]];
      const uint4 q1 = xv[edata[e + 8]];
      c0 = __hadd2(c0, uh2(q0.x)); c1 = __hadd2(c1, uh2(q0.y));
      c2 = __hadd2(c2, uh2(q0.z)); c3 = __hadd2(c3, uh2(q0.w));
      c0 = __hadd2(c0, uh2(q1.x)); c1 = __hadd2(c1, uh2(q1.y));
      c2 = __hadd2(c2, uh2(q1.z)); c3 = __hadd2(c3, uh2(q1.w));
    }
    if (e < end) {
      const uint4 q = xv[edata[e]];
      c0 = __hadd2(c0, uh2(q.x)); c1 = __hadd2(c1, uh2(q.y));
      c2 = __hadd2(c2, uh2(q.z)); c3 = __hadd2(c3, uh2(q.w));
    }
#pragma unroll
    for (int m = 1; m <= 4; m <<= 1) {
      c0 = __hadd2(c0, h2shfl_xor(c0, m));
      c1 = __hadd2(c1, h2shfl_xor(c1, m));
      c2 = __hadd2(c2, h2shfl_xor(c2, m));
      c3 = __hadd2(c3, h2shfl_xor(c3, m));
    }
    if (grp == 0) {
      const uint4 q = xv[node];
      c0 = __hadd2(c0, uh2(q.x)); c1 = __hadd2(c1, uh2(q.y));
      c2 = __hadd2(c2, uh2(q.z)); c3 = __hadd2(c3, uh2(q.w));
      const float dn = dinv[node];
      const float2 f0 = h22f2(c0), f1 = h22f2(c1);
      const float2 f2 = h22f2(c2), f3 = h22f2(c3);
      shagg[nl][0] = f0.x * dn; shagg[nl][1] = f0.y * dn;
      shagg[nl][2] = f1.x * dn; shagg[nl][3] = f1.y * dn;
      shagg[nl][4] = f2.x * dn; shagg[nl][5] = f2.y * dn;
      shagg[nl][6] = f3.x * dn; shagg[nl][7] = f3.y * dn;
    }
  }
  __syncthreads();
  {
    const int mn = tid >> 3;
    const int c = (tid & 7) * 8;
    if (node0 + mn < n) {
      float a[8] = {0, 0, 0, 0, 0, 0, 0, 0};
#pragma unroll
      for (int k = 0; k < 8; ++k) {
        const float s = shagg[mn][k];
#pragma unroll
        for (int j = 0; j < 8; ++j) a[j] += s * shw1[k * 64 + c + j];
      }
      float v[8];
#pragma unroll
      for (int j = 0; j < 8; ++j) {
        float t = a[j] * bn[c + j] + bn[64 + c + j];
        v[j] = t > 0.0f ? t : 0.0f;
      }
#pragma unroll
      for (int j = 0; j < 4; ++j)
        sht1[mn * 33 + (tid & 7) * 4 + j] = __floats2half2_rn(v[2 * j], v[2 * j + 1]);
    }
  }
  __syncthreads();
  const int cq = tid & 15;
  const int nbs = (tid >> 4) * 2;
  float acc[2][4];
#pragma unroll
  for (int j = 0; j < 2; ++j)
#pragma unroll
    for (int k = 0; k < 4; ++k) acc[j][k] = 0.0f;
  for (int kp = 0; kp < 32; ++kp) {
    const uint4 wq = shw2[kp * 16 + cq];
    const float2 w0 = h22f2(uh2(wq.x)), w1 = h22f2(uh2(wq.y));
    const float2 w2 = h22f2(uh2(wq.z)), w3 = h22f2(uh2(wq.w));
#pragma unroll
    for (int j = 0; j < 2; ++j) {
      const float2 s = h22f2(sht1[(nbs + j) * 33 + kp]);
      acc[j][0] += s.x * w0.x + s.y * w0.y;
      acc[j][1] += s.x * w1.x + s.y * w1.y;
      acc[j][2] += s.x * w2.x + s.y * w2.y;
      acc[j][3] += s.x * w3.x + s.y * w3.y;
    }
  }
#pragma unroll
  for (int j = 0; j < 2; ++j) {
    const int nd = node0 + nbs + j;
    if (nd < n) {
      const float dn = dinv[nd];
      uint2 o;
      o.x = f2u(acc[j][0] * dn, acc[j][1] * dn);
      o.y = f2u(acc[j][2] * dn, acc[j][3] * dn);
      reinterpret_cast<uint2*>(h2)[(size_t)nd * 16 + cq] = o;
    }
  }
}

// ============ gh64_mm3: gather h2' + dinv + BN2 + ReLU + mm3 + dinv, fused ============
// 16 nodes/block; 4 nodes/wave (2 groups x 8 qi-lanes); unroll-8 (full MLP batch).
__global__ void gh64_mm3(const __half* __restrict__ h, const float* __restrict__ dinv,
                         const int* __restrict__ rbeg, const int* __restrict__ rend,
                         const int* __restrict__ edata, const float* __restrict__ W3,
                         const float* __restrict__ bn, __half* __restrict__ h3, int n) {
  __shared__ int se[EDCAP_H64];        // 2.5 KB
  __shared__ __half2 shagg2[16 * 33];  // post-BN2+ReLU
  __shared__ __half2 shw3[32 * 32];    // [kp][c]
  __shared__ float shbn[128];          // sc2|sh2
  const int tid = threadIdx.x;
  const int node0 = blockIdx.x * 16;
  const int last = min(node0 + 15, n - 1);
  const int gb = rbeg[node0];
  const int total = rend[last] - gb;   // block's nodes are contiguous in edata (same bucket)
  const bool lds = (total <= EDCAP_H64);
  if (lds) {
    for (int i = tid; i < total; i += 256) se[i] = edata[gb + i];
  }
  for (int i = tid; i < 32 * 32; i += 256) {
    const int kp = i >> 5, c = i & 31;
    shw3[kp * 32 + c] = __floats2half2_rn(W3[(2 * kp) * 32 + c], W3[(2 * kp + 1) * 32 + c]);
  }
  if (tid < 128) shbn[tid] = bn[128 + tid];
  __syncthreads();
  // ---- gather phase: 4 nodes/wave; per node 2 groups x 8 qi-lanes; unroll-8 ----
  const int lane = tid & 63;
  const int node = node0 + ((tid >> 6) << 2) + (lane >> 4);
  const int sub = lane & 15;
  const int qi = sub & 7;     // uint4 index within 128B row
  const int grp = sub >> 3;   // 2 groups per node
  if (node < n) {
    const uint4* hv = reinterpret_cast<const uint4*>(h);
    __half2 c0 = __half2{0, 0}, c1 = c0, c2 = c0, c3 = c0;
    if (lds) {
      const int lbeg = rbeg[node] - gb, lend = rend[node] - gb;
      int e = lbeg + grp;
      // unroll-8: issue all ~8 of this lane's loads as one batch (deep MLP)
      for (; e + 14 < lend; e += 16) {
        const int s0 = se[e],     s1 = se[e + 2],  s2 = se[e + 4],  s3 = se[e + 6];
        const int s4 = se[e + 8], s5 = se[e + 10], s6 = se[e + 12], s7 = se[e + 14];
        const uint4 q0 = hv[(size_t)s0 * 8 + qi];
        const uint4 q1 = hv[(size_t)s1 * 8 + qi];
        const uint4 q2 = hv[(size_t)s2 * 8 + qi];
        const uint4 q3 = hv[(size_t)s3 * 8 + qi];
        const uint4 q4 = hv[(size_t)s4 * 8 + qi];
        const uint4 q5 = hv[(size_t)s5 * 8 + qi];
        const uint4 q6 = hv[(size_t)s6 * 8 + qi];
        const uint4 q7 = hv[(size_t)s7 * 8 + qi];
        c0 = __hadd2(c0, uh2(q0.x)); c1 = __hadd2(c1, uh2(q0.y));
        c2 = __hadd2(c2, uh2(q0.z)); c3 = __hadd2(c3, uh2(q0.w));
        c0 = __hadd2(c0, uh2(q1.x)); c1 = __hadd2(c1, uh2(q1.y));
        c2 = __hadd2(c2, uh2(q1.z)); c3 = __hadd2(c3, uh2(q1.w));
        c0 = __hadd2(c0, uh2(q2.x)); c1 = __hadd2(c1, uh2(q2.y));
        c2 = __hadd2(c2, uh2(q2.z)); c3 = __hadd2(c3, uh2(q2.w));
        c0 = __hadd2(c0, uh2(q3.x)); c1 = __hadd2(c1, uh2(q3.y));
        c2 = __hadd2(c2, uh2(q3.z)); c3 = __hadd2(c3, uh2(q3.w));
        c0 = __hadd2(c0, uh2(q4.x)); c1 = __hadd2(c1, uh2(q4.y));
        c2 = __hadd2(c2, uh2(q4.z)); c3 = __hadd2(c3, uh2(q4.w));
        c0 = __hadd2(c0, uh2(q5.x)); c1 = __hadd2(c1, uh2(q5.y));
        c2 = __hadd2(c2, uh2(q5.z)); c3 = __hadd2(c3, uh2(q5.w));
        c0 = __hadd2(c0, uh2(q6.x)); c1 = __hadd2(c1, uh2(q6.y));
        c2 = __hadd2(c2, uh2(q6.z)); c3 = __hadd2(c3, uh2(q6.w));
        c0 = __hadd2(c0, uh2(q7.x)); c1 = __hadd2(c1, uh2(q7.y));
        c2 = __hadd2(c2, uh2(q7.z)); c3 = __hadd2(c3, uh2(q7.w));
      }
      for (; e + 6 < lend; e += 8) {
        const int s0 = se[e], s1 = se[e + 2], s2 = se[e + 4], s3 = se[e + 6];
        const uint4 q0 = hv[(size_t)s0 * 8 + qi];
        const uint4 q1 = hv[(size_t)s1 * 8 + qi];
        const uint4 q2 = hv[(size_t)s2 * 8 + qi];
        const uint4 q3 = hv[(size_t)s3 * 8 + qi];
        c0 = __hadd2(c0, uh2(q0.x)); c1 = __hadd2(c1, uh2(q0.y));
        c2 = __hadd2(c2, uh2(q0.z)); c3 = __hadd2(c3, uh2(q0.w));
        c0 = __hadd2(c0, uh2(q1.x)); c1 = __hadd2(c1, uh2(q1.y));
        c2 = __hadd2(c2, uh2(q1.z)); c3 = __hadd2(c3, uh2(q1.w));
        c0 = __hadd2(c0, uh2(q2.x)); c1 = __hadd2(c1, uh2(q2.y));
        c2 = __hadd2(c2, uh2(q2.z)); c3 = __hadd2(c3, uh2(q2.w));
        c0 = __hadd2(c0, uh2(q3.x)); c1 = __hadd2(c1, uh2(q3.y));
        c2 = __hadd2(c2, uh2(q3.z)); c3 = __hadd2(c3, uh2(q3.w));
      }
      for (; e < lend; e += 2) {
        const uint4 q = hv[(size_t)se[e] * 8 + qi];
        c0 = __hadd2(c0, uh2(q.x)); c1 = __hadd2(c1, uh2(q.y));
        c2 = __hadd2(c2, uh2(q.z)); c3 = __hadd2(c3, uh2(q.w));
      }
    } else {
      const int beg = rbeg[node], end = rend[node];
      for (int e = beg + grp; e < end; e += 2) {
        const uint4 q = hv[(size_t)edata[e] * 8 + qi];
        c0 = __hadd2(c0, uh2(q.x)); c1 = __hadd2(c1, uh2(q.y));
        c2 = __hadd2(c2, uh2(q.z)); c3 = __hadd2(c3, uh2(q.w));
      }
    }
    // reduce across 2 groups (lane bit 3)
    c0 = __hadd2(c0, h2shfl_xor(c0, 8));
    c1 = __hadd2(c1, h2shfl_xor(c1, 8));
    c2 = __hadd2(c2, h2shfl_xor(c2, 8));
    c3 = __hadd2(c3, h2shfl_xor(c3, 8));
    if (grp == 0) {
      const uint4 q = hv[(size_t)node * 8 + qi];  // self term
      c0 = __hadd2(c0, uh2(q.x)); c1 = __hadd2(c1, uh2(q.y));
      c2 = __hadd2(c2, uh2(q.z)); c3 = __hadd2(c3, uh2(q.w));
      const float dn = dinv[node];
      const int nl = node - node0;
      const float2 f[4] = {h22f2(c0), h22f2(c1), h22f2(c2), h22f2(c3)};
#pragma unroll
      for (int j = 0; j < 4; ++j) {
        const int ch = qi * 8 + 2 * j;
        float v0 = f[j].x * dn * shbn[ch] + shbn[64 + ch];
        float v1 = f[j].y * dn * shbn[ch + 1] + shbn[64 + ch + 1];
        v0 = v0 > 0.0f ? v0 : 0.0f;
        v1 = v1 > 0.0f ? v1 : 0.0f;
        shagg2[nl * 33 + qi * 4 + j] = __floats2half2_rn(v0, v1);
      }
    }
  }
  __syncthreads();
  // ---- mm3 phase: all 256 threads; each handles 2 nodes (nl, nl+8) x 1 channel ----
  const int c = tid & 31;
#pragma unroll
  for (int j = 0; j < 2; ++j) {
    const int nl = (tid >> 5) + 8 * j;
    const int mnode = node0 + nl;
    float acc = 0.0f;
#pragma unroll 8
    for (int kp = 0; kp < 32; ++kp) {
      const float2 s = h22f2(shagg2[nl * 33 + kp]);
      const float2 w = h22f2(shw3[kp * 32 + c]);
      acc += s.x * w.x + s.y * w.y;
    }
    float outv = 0.0f;
    if (mnode < n) outv = acc * dinv[mnode];
    const float partner = __shfl_xor(outv, 1);
    if ((c & 1) == 0 && mnode < n) {
      reinterpret_cast<unsigned*>(h3)[(size_t)mnode * 16 + (c >> 1)] = f2u(outv, partner);
    }
  }
}

// ============ gather h3' (C=32) + BN3 + ReLU + 32x2 linear + log_softmax ============
__global__ void gather_cls(const __half* __restrict__ h, const float* __restrict__ dinv,
                           const int* __restrict__ rbeg, const int* __restrict__ rend,
                           const int* __restrict__ edata, const float* __restrict__ bn,
                           const float* __restrict__ Wc, const float* __restrict__ bc,
                           float* __restrict__ out, int n) {
  __shared__ int se[EDCAP_CLS];
  const int tid = threadIdx.x;
  const int node0 = blockIdx.x * 16;
  const int last = min(node0 + 15, n - 1);
  const int gb = rbeg[node0];
  const int total = rend[last] - gb;
  const bool lds = (total <= EDCAP_CLS);
  if (lds) {
    for (int i = tid; i < total; i += 256) se[i] = edata[gb + i];
  }
  __syncthreads();
  const int lane = tid & 63;
  const int node = node0 + ((tid >> 6) << 2) + (lane >> 4);
  if (node >= n) return;
  const int qi = lane & 3;
  const int grp = (lane >> 2) & 3;
  const uint4* hv = reinterpret_cast<const uint4*>(h);
  __half2 c0 = __half2{0, 0}, c1 = c0, c2 = c0, c3 = c0;
  if (lds) {
    const int beg = rbeg[node] - gb, end = rend[node] - gb;
    int e = beg + grp;
    for (; e + 12 < end; e += 16) {
      const int s0 = se[e], s1 = se[e + 4], s2 = se[e + 8], s3 = se[e + 12];
      const uint4 q0 = hv[(size_t)s0 * 4 + qi];
      const uint4 q1 = hv[(size_t)s1 * 4 + qi];
      const uint4 q2 = hv[(size_t)s2 * 4 + qi];
      const uint4 q3 = hv[(size_t)s3 * 4 + qi];
      c0 = __hadd2(c0, uh2(q0.x)); c1 = __hadd2(c1, uh2(q0.y));
      c2 = __hadd2(c2, uh2(q0.z)); c3 = __hadd2(c3, uh2(q0.w));
      c0 = __hadd2(c0, uh2(q1.x)); c1 = __hadd2(c1, uh2(q1.y));
      c2 = __hadd2(c2, uh2(q1.z)); c3 = __hadd2(c3, uh2(q1.w));
      c0 = __hadd2(c0, uh2(q2.x)); c1 = __hadd2(c1, uh2(q2.y));
      c2 = __hadd2(c2, uh2(q2.z)); c3 = __hadd2(c3, uh2(q2.w));
      c0 = __hadd2(c0, uh2(q3.x)); c1 = __hadd2(c1, uh2(q3.y));
      c2 = __hadd2(c2, uh2(q3.z)); c3 = __hadd2(c3, uh2(q3.w));
    }
    for (; e < end; e += 4) {
      const uint4 q = hv[(size_t)se[e] * 4 + qi];
      c0 = __hadd2(c0, uh2(q.x)); c1 = __hadd2(c1, uh2(q.y));
      c2 = __hadd2(c2, uh2(q.z)); c3 = __hadd2(c3, uh2(q.w));
    }
  } else {
    const int beg = rbeg[node], end = rend[node];
    int e = beg + grp;
    for (; e + 12 < end; e += 16) {
      const int s0 = edata[e], s1 = edata[e + 4], s2 = edata[e + 8], s3 = edata[e + 12];
      const uint4 q0 = hv[(size_t)s0 * 4 + qi];
      const uint4 q1 = hv[(size_t)s1 * 4 + qi];
      const uint4 q2 = hv[(size_t)s2 * 4 + qi];
      const uint4 q3 = hv[(size_t)s3 * 4 + qi];
      c0 = __hadd2(c0, uh2(q0.x)); c1 = __hadd2(c1, uh2(q0.y));
      c2 = __hadd2(c2, uh2(q0.z)); c3 = __hadd2(c3, uh2(q0.w));
      c0 = __hadd2(c0, uh2(q1.x)); c1 = __hadd2(c1, uh2(q1.y));
      c2 = __hadd2(c2, uh2(q1.z)); c3 = __hadd2(c3, uh2(q1.w));
      c0 = __hadd2(c0, uh2(q2.x)); c1 = __hadd2(c1, uh2(q2.y));
      c2 = __hadd2(c2, uh2(q2.z)); c3 = __hadd2(c3, uh2(q2.w));
      c0 = __hadd2(c0, uh2(q3.x)); c1 = __hadd2(c1, uh2(q3.y));
      c2 = __hadd2(c2, uh2(q3.z)); c3 = __hadd2(c3, uh2(q3.w));
    }
    for (; e < end; e += 4) {
      const uint4 q = hv[(size_t)edata[e] * 4 + qi];
      c0 = __hadd2(c0, uh2(q.x)); c1 = __hadd2(c1, uh2(q.y));
      c2 = __hadd2(c2, uh2(q.z)); c3 = __hadd2(c3, uh2(q.w));
    }
  }
#pragma unroll
  for (int m = 4; m <= 8; m <<= 1) {
    c0 = __hadd2(c0, h2shfl_xor(c0, m));
    c1 = __hadd2(c1, h2shfl_xor(c1, m));
    c2 = __hadd2(c2, h2shfl_xor(c2, m));
    c3 = __hadd2(c3, h2shfl_xor(c3, m));
  }
  if (grp != 0) return;
  // self term
  {
    const uint4 q = hv[(size_t)node * 4 + qi];
    c0 = __hadd2(c0, uh2(q.x)); c1 = __hadd2(c1, uh2(q.y));
    c2 = __hadd2(c2, uh2(q.z)); c3 = __hadd2(c3, uh2(q.w));
  }
  const float dn = dinv[node];
  const float2 f0 = h22f2(c0), f1 = h22f2(c1);
  const float2 f2 = h22f2(c2), f3 = h22f2(c3);
  const float v[8] = {f0.x * dn, f0.y * dn, f1.x * dn, f1.y * dn,
                      f2.x * dn, f2.y * dn, f3.x * dn, f3.y * dn};
  float l0 = 0.0f, l1 = 0.0f;
#pragma unroll
  for (int j = 0; j < 8; ++j) {
    const int c = qi * 8 + j;
    float t = v[j] * bn[256 + c] + bn[288 + c];
    t = t > 0.0f ? t : 0.0f;
    const float2 w = *reinterpret_cast<const float2*>(&Wc[c * 2]);
    l0 += t * w.x;
    l1 += t * w.y;
  }
  l0 += __shfl_xor(l0, 1); l1 += __shfl_xor(l1, 1);
  l0 += __shfl_xor(l0, 2); l1 += __shfl_xor(l1, 2);
  if (qi == 0) {
    l0 += bc[0];
    l1 += bc[1];
    const float m = fmaxf(l0, l1);
    const float lse = m + log1pf(expf(-fabsf(l0 - l1)));
    *reinterpret_cast<float2*>(&out[(size_t)node * 2]) = make_float2(l0 - lse, l1 - lse);
  }
}

// ============ launch ============
extern "C" void kernel_launch(void* const* d_in, const int* in_sizes, int n_in,
                              void* d_out, int out_size, void* d_ws, size_t ws_size,
                              hipStream_t stream) {
  const float* x  = (const float*)d_in[0];
  const int* ei   = (const int*)d_in[1];   // int32 on device per harness contract
  const float* W1 = (const float*)d_in[2];
  const float* b1 = (const float*)d_in[3];
  const float* g1 = (const float*)d_in[4];
  const float* be1 = (const float*)d_in[5];
  const float* rm1 = (const float*)d_in[6];
  const float* rv1 = (const float*)d_in[7];
  const float* W2 = (const float*)d_in[8];
  const float* b2 = (const float*)d_in[9];
  const float* g2 = (const float*)d_in[10];
  const float* be2 = (const float*)d_in[11];
  const float* rm2 = (const float*)d_in[12];
  const float* rv2 = (const float*)d_in[13];
  const float* W3 = (const float*)d_in[14];
  const float* b3 = (const float*)d_in[15];
  const float* g3 = (const float*)d_in[16];
  const float* be3 = (const float*)d_in[17];
  const float* rm3 = (const float*)d_in[18];
  const float* rv3 = (const float*)d_in[19];
  const float* Wc = (const float*)d_in[20];
  const float* bc = (const float*)d_in[21];

  const int N_ = in_sizes[0] / 8;
  const int E_ = in_sizes[1] / 2;
  const int NB = (N_ + 255) >> 8;

  auto align = [](size_t v) { return (v + 255) & ~(size_t)255; };
  char* ws = (char*)d_ws;
  size_t off = 0;
  float* dinv   = (float*)(ws + off); off += align((size_t)N_ * 4);
  int* bcur     = (int*)(ws + off);   off += align(((size_t)NB + 1) * 4);
  int* rbeg     = (int*)(ws + off);   off += align((size_t)N_ * 4);
  int* rend     = (int*)(ws + off);   off += align((size_t)N_ * 4);
  float* bnbuf  = (float*)(ws + off); off += align(320 * 4);
  int* edata    = (int*)(ws + off);   off += align((size_t)E_ * 4);
  __half* xs    = (__half*)(ws + off); off += align((size_t)N_ * 8 * 2);
  char* regionA = ws + off;           off += align((size_t)NB * BCAP * 4);
  char* regionB = ws + off;           off += align((size_t)N_ * 64 * 2);

  int* bucketbuf = (int*)regionA;
  __half* h3   = (__half*)regionA;   // after p2_sort consumed bucketbuf
  __half* h2   = (__half*)regionB;
  int* gcursor = bcur + NB;

  prep<<<1 + (NB + 1 + 255) / 256, 256, 0, stream>>>(b1, g1, be1, rm1, rv1,
                                                     b2, g2, be2, rm2, rv2,
                                                     b3, g3, be3, rm3, rv3, bnbuf, bcur, NB);
  p1_partition<<<(E_ + 4095) / 4096, 256, 0, stream>>>(ei, bucketbuf, bcur, E_, NB);
  p2_sort<<<NB, 256, 0, stream>>>(bucketbuf, bcur, gcursor, edata, rbeg, rend,
                                  dinv, x, (__half2*)xs, N_);

  l12<<<(N_ + 31) / 32, 256, 0, stream>>>(xs, dinv, rbeg, rend, edata, W1, W2, bnbuf, h2, N_);

  gh64_mm3<<<(N_ + 15) / 16, 256, 0, stream>>>(h2, dinv, rbeg, rend, edata, W3, bnbuf, h3, N_);

  gather_cls<<<(N_ + 15) / 16, 256, 0, stream>>>(h3, dinv, rbeg, rend, edata,
                                                 bnbuf, Wc, bc, (float*)d_out, N_);
}

// Round 17
// 138.745 us; speedup vs baseline: 1.3486x; 1.0608x over previous
//
#include <hip/hip_runtime.h>
#include <hip/hip_fp16.h>

#define BN_EPS 1e-5f
#define BCAP 5120        // bucket capacity (mean 4096 edges/bucket)
#define EDCAP_H64 640    // LDS edge staging, gh64_mm3: 16 nodes/block (mean 256)
#define EDCAP_CLS 1280   // LDS edge staging, gather_cls: 16 nodes/block (mean 256)

__device__ __forceinline__ unsigned f2u(float a, float b) {
  __half2 h = __floats2half2_rn(a, b);
  return *reinterpret_cast<unsigned*>(&h);
}
__device__ __forceinline__ __half2 uh2(unsigned u) {
  return *reinterpret_cast<__half2*>(&u);
}
__device__ __forceinline__ float2 h22f2(__half2 h) { return __half22float2(h); }
__device__ __forceinline__ __half2 h2shfl_xor(__half2 v, int m) {
  int i = *reinterpret_cast<int*>(&v);
  i = __shfl_xor(i, m);
  return *reinterpret_cast<__half2*>(&i);
}

// ============ prep: block 0 computes BN constants + fp16 weight packs; others zero bcur ============
// bn layout: sc1[64] | sh1[64] | sc2[64] | sh2[64] | sc3[32] | sh3[32]
// w2h: half2[kp*64+c] = (W2[2kp][c], W2[2kp+1][c]);  w3h: half2[kp*32+c]
__global__ void prep(const float* __restrict__ b1, const float* __restrict__ g1,
                     const float* __restrict__ be1, const float* __restrict__ rm1,
                     const float* __restrict__ rv1,
                     const float* __restrict__ b2, const float* __restrict__ g2,
                     const float* __restrict__ be2, const float* __restrict__ rm2,
                     const float* __restrict__ rv2,
                     const float* __restrict__ b3, const float* __restrict__ g3,
                     const float* __restrict__ be3, const float* __restrict__ rm3,
                     const float* __restrict__ rv3,
                     const float* __restrict__ W2, const float* __restrict__ W3,
                     float* __restrict__ bn, __half2* __restrict__ w2h,
                     __half2* __restrict__ w3h, int* __restrict__ bcur, int NB) {
  if (blockIdx.x == 0) {
    const int t = threadIdx.x;
    if (t < 64) {
      const float s = g1[t] * rsqrtf(rv1[t] + BN_EPS);
      bn[t] = s;
      bn[64 + t] = (b1[t] - rm1[t]) * s + be1[t];
    } else if (t < 128) {
      const int c = t - 64;
      const float s = g2[c] * rsqrtf(rv2[c] + BN_EPS);
      bn[128 + c] = s;
      bn[192 + c] = (b2[c] - rm2[c]) * s + be2[c];
    } else if (t < 160) {
      const int c = t - 128;
      const float s = g3[c] * rsqrtf(rv3[c] + BN_EPS);
      bn[256 + c] = s;
      bn[288 + c] = (b3[c] - rm3[c]) * s + be3[c];
    }
    for (int i = t; i < 2048; i += 256) {        // W2 pack
      const int kp = i >> 6, c = i & 63;
      w2h[i] = __floats2half2_rn(W2[(2 * kp) * 64 + c], W2[(2 * kp + 1) * 64 + c]);
    }
    for (int i = t; i < 1024; i += 256) {        // W3 pack
      const int kp = i >> 5, c = i & 31;
      w3h[i] = __floats2half2_rn(W3[(2 * kp) * 32 + c], W3[(2 * kp + 1) * 32 + c]);
    }
  } else {
    const int i = (blockIdx.x - 1) * 256 + threadIdx.x;
    if (i <= NB) bcur[i] = 0;  // includes the global cursor at bcur[NB]
  }
}

// ============ Phase 1: partition edges into per-bucket regions (bucket = dst>>8) ============
// int2-vectorized ei reads (both halves); 4096-edge chunks keep int2 alignment.
__global__ void p1_partition(const int* __restrict__ ei, int* __restrict__ bucketbuf,
                             int* __restrict__ bcur, int E_, int NB) {
  __shared__ int pk[4096];
  __shared__ short bk[4096];
  __shared__ int hist[512];
  __shared__ int bbase[512];
  const int tid = threadIdx.x;
  const int e0 = blockIdx.x * 4096;
  const int ecount = min(4096, E_ - e0);
  for (int i = tid; i < NB; i += 256) hist[i] = 0;
  __syncthreads();
  const int epairs = ecount >> 1;
  const int2* sp = reinterpret_cast<const int2*>(ei + e0);
  const int2* dp = reinterpret_cast<const int2*>(ei + (size_t)E_ + e0);
  for (int i = tid; i < epairs; i += 256) {
    const int2 s2 = sp[i];
    const int2 d2 = dp[i];
    const int i0 = 2 * i, i1 = 2 * i + 1;
    pk[i0] = ((d2.x & 255) << 24) | s2.x;   // src < 2^24 (N = 100000)
    pk[i1] = ((d2.y & 255) << 24) | s2.y;
    const int b0 = d2.x >> 8, b1_ = d2.y >> 8;
    bk[i0] = (short)b0;
    bk[i1] = (short)b1_;
    atomicAdd(&hist[b0], 1);
    atomicAdd(&hist[b1_], 1);
  }
  if ((ecount & 1) && tid == 0) {  // odd tail (cannot happen for E=1.6M, kept for safety)
    const int i = ecount - 1;
    const int s = ei[e0 + i];
    const int d = ei[(size_t)E_ + e0 + i];
    pk[i] = ((d & 255) << 24) | s;
    bk[i] = (short)(d >> 8);
    atomicAdd(&hist[d >> 8], 1);
  }
  __syncthreads();
  for (int i = tid; i < NB; i += 256) {
    const int c = hist[i];
    bbase[i] = c ? atomicAdd(&bcur[i], c) : 0;
    hist[i] = 0;  // reuse as local cursor
  }
  __syncthreads();
  for (int i = tid; i < ecount; i += 256) {
    const int b = bk[i];
    const int slot = bbase[b] + atomicAdd(&hist[b], 1);
    bucketbuf[(size_t)b * BCAP + slot] = pk[i];
  }
}

// ============ Phase 2: per-bucket counting sort (512 threads); emits rbeg/rend, dinv, xs ============
__global__ void p2_sort(const int* __restrict__ bucketbuf, const int* __restrict__ bcur,
                        int* __restrict__ gcursor, int* __restrict__ edata,
                        int* __restrict__ rbeg, int* __restrict__ rend,
                        float* __restrict__ dinv, const float* __restrict__ x,
                        __half2* __restrict__ xs, int N_) {
  __shared__ int cntl[256];
  __shared__ int scn[256];
  __shared__ int cur[256];
  __shared__ float dinvl[256];
  __shared__ int sbuf[BCAP];
  __shared__ int sbase;
  const int b = blockIdx.x;
  const int tid = threadIdx.x;           // 0..511
  const int m = bcur[b];
  const int* srcp = bucketbuf + (size_t)b * BCAP;
  if (tid < 256) cntl[tid] = 0;
  __syncthreads();
  for (int i = tid; i < m; i += 512) atomicAdd(&cntl[(unsigned)srcp[i] >> 24], 1);
  __syncthreads();
  if (tid == 0) sbase = atomicAdd(gcursor, m);  // order-free range claim
  const int cnt = (tid < 256) ? cntl[tid] : 0;
  if (tid < 256) scn[tid] = cnt;
  __syncthreads();
  for (int off = 1; off < 256; off <<= 1) {
    const int u = (tid < 256 && tid >= off) ? scn[tid - off] : 0;
    __syncthreads();
    if (tid < 256) scn[tid] += u;
    __syncthreads();
  }
  const int base = sbase;
  if (tid < 256) {
    const int excl = scn[tid] - cnt;
    cur[tid] = excl;
    const int node = (b << 8) + tid;
    const float dn = rsqrtf((float)cnt + 1.0f);  // deg = in-degree + self-loop
    dinvl[tid] = dn;
    if (node < N_) {
      rbeg[node] = base + excl;
      rend[node] = base + excl + cnt;
      dinv[node] = dn;
    }
  }
  __syncthreads();
  for (int i = tid; i < m; i += 512) {
    const int v = srcp[i];
    const int slot = atomicAdd(&cur[(unsigned)v >> 24], 1);
    sbuf[slot] = v & 0xFFFFFF;
  }
  __syncthreads();
  for (int i = tid; i < m; i += 512) edata[(size_t)base + i] = sbuf[i];
  // fused: xs = fp16(dinv * x) for this bucket's 256 nodes (coalesced x reads)
  const int nb0 = b << 8;
  for (int i = tid; i < 1024; i += 512) {
    const int nd = nb0 + (i >> 2);
    if (nd < N_) {
      const float d2 = dinvl[i >> 2];
      const float2 v2 = reinterpret_cast<const float2*>(x)[(size_t)nd * 4 + (i & 3)];
      xs[(size_t)nd * 4 + (i & 3)] = __floats2half2_rn(v2.x * d2, v2.y * d2);
    }
  }
}

// ============ l12: gather(xs) + mm1 + BN1 + ReLU + mm2 + dinv, fully fused ============
// Block = 256 threads = 32 nodes. t1 lives only in LDS. W2 preconverted (w2h).
__global__ void l12(const __half* __restrict__ xs, const float* __restrict__ dinv,
                    const int* __restrict__ rbeg, const int* __restrict__ rend,
                    const int* __restrict__ edata, const float* __restrict__ W1,
                    const __half2* __restrict__ w2h, const float* __restrict__ bn,
                    __half* __restrict__ h2, int n) {
  __shared__ float shw1[8 * 64];
  __shared__ float shagg[32][8];
  __shared__ __half2 sht1[32 * 33];
  __shared__ uint4 shw2[32 * 16];
  const int tid = threadIdx.x;
  const int node0 = blockIdx.x * 32;
  for (int i = tid; i < 512; i += 256) shw1[i] = W1[i];
  for (int i = tid; i < 512; i += 256)
    shw2[i] = reinterpret_cast<const uint4*>(w2h)[i];
  const int lane = tid & 63;
  const int nl = ((tid >> 6) << 3) + (lane >> 3);
  const int grp = lane & 7;
  const int node = node0 + nl;
  if (node < n) {
    const int beg = rbeg[node], end = rend[node];
    const uint4* xv = reinterpret_cast<const uint4*>(xs);
    __half2 c0 = __half2{0, 0}, c1 = c0, c2 = c0, c3 = c0;
    int e = beg + grp;
    for (; e + 8 < end; e += 16) {
      const uint4 q0 = xv[edata[e]];
      const uint4 q1 = xv[edata[e + 8]];
      c0 = __hadd2(c0, uh2(q0.x)); c1 = __hadd2(c1, uh2(q0.y));
      c2 = __hadd2(c2, uh2(q0.z)); c3 = __hadd2(c3, uh2(q0.w));
      c0 = __hadd2(c0, uh2(q1.x)); c1 = __hadd2(c1, uh2(q1.y));
      c2 = __hadd2(c2, uh2(q1.z)); c3 = __hadd2(c3, uh2(q1.w));
    }
    if (e < end) {
      const uint4 q = xv[edata[e]];
      c0 = __hadd2(c0, uh2(q.x)); c1 = __hadd2(c1, uh2(q.y));
      c2 = __hadd2(c2, uh2(q.z)); c3 = __hadd2(c3, uh2(q.w));
    }
#pragma unroll
    for (int m = 1; m <= 4; m <<= 1) {
      c0 = __hadd2(c0, h2shfl_xor(c0, m));
      c1 = __hadd2(c1, h2shfl_xor(c1, m));
      c2 = __hadd2(c2, h2shfl_xor(c2, m));
      c3 = __hadd2(c3, h2shfl_xor(c3, m));
    }
    if (grp == 0) {
      const uint4 q = xv[node];
      c0 = __hadd2(c0, uh2(q.x)); c1 = __hadd2(c1, uh2(q.y));
      c2 = __hadd2(c2, uh2(q.z)); c3 = __hadd2(c3, uh2(q.w));
      const float dn = dinv[node];
      const float2 f0 = h22f2(c0), f1 = h22f2(c1);
      const float2 f2 = h22f2(c2), f3 = h22f2(c3);
      shagg[nl][0] = f0.x * dn; shagg[nl][1] = f0.y * dn;
      shagg[nl][2] = f1.x * dn; shagg[nl][3] = f1.y * dn;
      shagg[nl][4] = f2.x * dn; shagg[nl][5] = f2.y * dn;
      shagg[nl][6] = f3.x * dn; shagg[nl][7] = f3.y * dn;
    }
  }
  __syncthreads();
  {
    const int mn = tid >> 3;
    const int c = (tid & 7) * 8;
    if (node0 + mn < n) {
      float a[8] = {0, 0, 0, 0, 0, 0, 0, 0};
#pragma unroll
      for (int k = 0; k < 8; ++k) {
        const float s = shagg[mn][k];
#pragma unroll
        for (int j = 0; j < 8; ++j) a[j] += s * shw1[k * 64 + c + j];
      }
      float v[8];
#pragma unroll
      for (int j = 0; j < 8; ++j) {
        float t = a[j] * bn[c + j] + bn[64 + c + j];
        v[j] = t > 0.0f ? t : 0.0f;
      }
#pragma unroll
      for (int j = 0; j < 4; ++j)
        sht1[mn * 33 + (tid & 7) * 4 + j] = __floats2half2_rn(v[2 * j], v[2 * j + 1]);
    }
  }
  __syncthreads();
  const int cq = tid & 15;
  const int nbs = (tid >> 4) * 2;
  float acc[2][4];
#pragma unroll
  for (int j = 0; j < 2; ++j)
#pragma unroll
    for (int k = 0; k < 4; ++k) acc[j][k] = 0.0f;
  for (int kp = 0; kp < 32; ++kp) {
    const uint4 wq = shw2[kp * 16 + cq];
    const float2 w0 = h22f2(uh2(wq.x)), w1 = h22f2(uh2(wq.y));
    const float2 w2 = h22f2(uh2(wq.z)), w3 = h22f2(uh2(wq.w));
#pragma unroll
    for (int j = 0; j < 2; ++j) {
      const float2 s = h22f2(sht1[(nbs + j) * 33 + kp]);
      acc[j][0] += s.x * w0.x + s.y * w0.y;
      acc[j][1] += s.x * w1.x + s.y * w1.y;
      acc[j][2] += s.x * w2.x + s.y * w2.y;
      acc[j][3] += s.x * w3.x + s.y * w3.y;
    }
  }
#pragma unroll
  for (int j = 0; j < 2; ++j) {
    const int nd = node0 + nbs + j;
    if (nd < n) {
      const float dn = dinv[nd];
      uint2 o;
      o.x = f2u(acc[j][0] * dn, acc[j][1] * dn);
      o.y = f2u(acc[j][2] * dn, acc[j][3] * dn);
      reinterpret_cast<uint2*>(h2)[(size_t)nd * 16 + cq] = o;
    }
  }
}

// ============ gh64_mm3: gather h2' + dinv + BN2 + ReLU + mm3 + dinv, fused ============
// 16 nodes/block; 4 nodes/wave (2 groups x 8 qi-lanes); W3 preconverted (w3h).
__global__ void gh64_mm3(const __half* __restrict__ h, const float* __restrict__ dinv,
                         const int* __restrict__ rbeg, const int* __restrict__ rend,
                         const int* __restrict__ edata, const __half2* __restrict__ w3h,
                         const float* __restrict__ bn, __half* __restrict__ h3, int n) {
  __shared__ int se[EDCAP_H64];        // 2.5 KB
  __shared__ __half2 shagg2[16 * 33];  // post-BN2+ReLU
  __shared__ __half2 shw3[32 * 32];    // [kp][c]
  __shared__ float shbn[128];          // sc2|sh2
  const int tid = threadIdx.x;
  const int node0 = blockIdx.x * 16;
  const int last = min(node0 + 15, n - 1);
  const int gb = rbeg[node0];
  const int total = rend[last] - gb;   // block's nodes are contiguous in edata (same bucket)
  const bool lds = (total <= EDCAP_H64);
  if (lds) {
    for (int i = tid; i < total; i += 256) se[i] = edata[gb + i];
  }
  for (int i = tid; i < 256; i += 256)
    reinterpret_cast<uint4*>(shw3)[i + tid - tid] = reinterpret_cast<const uint4*>(w3h)[i];
  for (int i = tid + 256; i < 256; ) { }  // (no-op; single pass covers 256 uint4 = 4KB)
  if (tid < 128) shbn[tid] = bn[128 + tid];
  __syncthreads();
  // ---- gather phase: 4 nodes/wave; per node 2 groups x 8 qi-lanes; unroll-4 ----
  const int lane = tid & 63;
  const int node = node0 + ((tid >> 6) << 2) + (lane >> 4);
  const int sub = lane & 15;
  const int qi = sub & 7;     // uint4 index within 128B row
  const int grp = sub >> 3;   // 2 groups per node
  if (node < n) {
    const uint4* hv = reinterpret_cast<const uint4*>(h);
    __half2 c0 = __half2{0, 0}, c1 = c0, c2 = c0, c3 = c0;
    if (lds) {
      const int lbeg = rbeg[node] - gb, lend = rend[node] - gb;
      int e = lbeg + grp;
      for (; e + 6 < lend; e += 8) {
        const int s0 = se[e], s1 = se[e + 2], s2 = se[e + 4], s3 = se[e + 6];
        const uint4 q0 = hv[(size_t)s0 * 8 + qi];
        const uint4 q1 = hv[(size_t)s1 * 8 + qi];
        const uint4 q2 = hv[(size_t)s2 * 8 + qi];
        const uint4 q3 = hv[(size_t)s3 * 8 + qi];
        c0 = __hadd2(c0, uh2(q0.x)); c1 = __hadd2(c1, uh2(q0.y));
        c2 = __hadd2(c2, uh2(q0.z)); c3 = __hadd2(c3, uh2(q0.w));
        c0 = __hadd2(c0, uh2(q1.x)); c1 = __hadd2(c1, uh2(q1.y));
        c2 = __hadd2(c2, uh2(q1.z)); c3 = __hadd2(c3, uh2(q1.w));
        c0 = __hadd2(c0, uh2(q2.x)); c1 = __hadd2(c1, uh2(q2.y));
        c2 = __hadd2(c2, uh2(q2.z)); c3 = __hadd2(c3, uh2(q2.w));
        c0 = __hadd2(c0, uh2(q3.x)); c1 = __hadd2(c1, uh2(q3.y));
        c2 = __hadd2(c2, uh2(q3.z)); c3 = __hadd2(c3, uh2(q3.w));
      }
      for (; e < lend; e += 2) {
        const uint4 q = hv[(size_t)se[e] * 8 + qi];
        c0 = __hadd2(c0, uh2(q.x)); c1 = __hadd2(c1, uh2(q.y));
        c2 = __hadd2(c2, uh2(q.z)); c3 = __hadd2(c3, uh2(q.w));
      }
    } else {
      const int beg = rbeg[node], end = rend[node];
      for (int e = beg + grp; e < end; e += 2) {
        const uint4 q = hv[(size_t)edata[e] * 8 + qi];
        c0 = __hadd2(c0, uh2(q.x)); c1 = __hadd2(c1, uh2(q.y));
        c2 = __hadd2(c2, uh2(q.z)); c3 = __hadd2(c3, uh2(q.w));
      }
    }
    // reduce across 2 groups (lane bit 3)
    c0 = __hadd2(c0, h2shfl_xor(c0, 8));
    c1 = __hadd2(c1, h2shfl_xor(c1, 8));
    c2 = __hadd2(c2, h2shfl_xor(c2, 8));
    c3 = __hadd2(c3, h2shfl_xor(c3, 8));
    if (grp == 0) {
      const uint4 q = hv[(size_t)node * 8 + qi];  // self term
      c0 = __hadd2(c0, uh2(q.x)); c1 = __hadd2(c1, uh2(q.y));
      c2 = __hadd2(c2, uh2(q.z)); c3 = __hadd2(c3, uh2(q.w));
      const float dn = dinv[node];
      const int nl = node - node0;
      const float2 f[4] = {h22f2(c0), h22f2(c1), h22f2(c2), h22f2(c3)};
#pragma unroll
      for (int j = 0; j < 4; ++j) {
        const int ch = qi * 8 + 2 * j;
        float v0 = f[j].x * dn * shbn[ch] + shbn[64 + ch];
        float v1 = f[j].y * dn * shbn[ch + 1] + shbn[64 + ch + 1];
        v0 = v0 > 0.0f ? v0 : 0.0f;
        v1 = v1 > 0.0f ? v1 : 0.0f;
        shagg2[nl * 33 + qi * 4 + j] = __floats2half2_rn(v0, v1);
      }
    }
  }
  __syncthreads();
  // ---- mm3 phase: all 256 threads; each handles 2 nodes (nl, nl+8) x 1 channel ----
  const int c = tid & 31;
#pragma unroll
  for (int j = 0; j < 2; ++j) {
    const int nl = (tid >> 5) + 8 * j;
    const int mnode = node0 + nl;
    float acc = 0.0f;
#pragma unroll 8
    for (int kp = 0; kp < 32; ++kp) {
      const float2 s = h22f2(shagg2[nl * 33 + kp]);
      const float2 w = h22f2(shw3[kp * 32 + c]);
      acc += s.x * w.x + s.y * w.y;
    }
    float outv = 0.0f;
    if (mnode < n) outv = acc * dinv[mnode];
    const float partner = __shfl_xor(outv, 1);
    if ((c & 1) == 0 && mnode < n) {
      reinterpret_cast<unsigned*>(h3)[(size_t)mnode * 16 + (c >> 1)] = f2u(outv, partner);
    }
  }
}

// ============ gather h3' (C=32) + BN3 + ReLU + 32x2 linear + log_softmax ============
__global__ void gather_cls(const __half* __restrict__ h, const float* __restrict__ dinv,
                           const int* __restrict__ rbeg, const int* __restrict__ rend,
                           const int* __restrict__ edata, const float* __restrict__ bn,
                           const float* __restrict__ Wc, const float* __restrict__ bc,
                           float* __restrict__ out, int n) {
  __shared__ int se[EDCAP_CLS];
  const int tid = threadIdx.x;
  const int node0 = blockIdx.x * 16;
  const int last = min(node0 + 15, n - 1);
  const int gb = rbeg[node0];
  const int total = rend[last] - gb;
  const bool lds = (total <= EDCAP_CLS);
  if (lds) {
    for (int i = tid; i < total; i += 256) se[i] = edata[gb + i];
  }
  __syncthreads();
  const int lane = tid & 63;
  const int node = node0 + ((tid >> 6) << 2) + (lane >> 4);
  if (node >= n) return;
  const int qi = lane & 3;
  const int grp = (lane >> 2) & 3;
  const uint4* hv = reinterpret_cast<const uint4*>(h);
  __half2 c0 = __half2{0, 0}, c1 = c0, c2 = c0, c3 = c0;
  if (lds) {
    const int beg = rbeg[node] - gb, end = rend[node] - gb;
    int e = beg + grp;
    for (; e + 12 < end; e += 16) {
      const int s0 = se[e], s1 = se[e + 4], s2 = se[e + 8], s3 = se[e + 12];
      const uint4 q0 = hv[(size_t)s0 * 4 + qi];
      const uint4 q1 = hv[(size_t)s1 * 4 + qi];
      const uint4 q2 = hv[(size_t)s2 * 4 + qi];
      const uint4 q3 = hv[(size_t)s3 * 4 + qi];
      c0 = __hadd2(c0, uh2(q0.x)); c1 = __hadd2(c1, uh2(q0.y));
      c2 = __hadd2(c2, uh2(q0.z)); c3 = __hadd2(c3, uh2(q0.w));
      c0 = __hadd2(c0, uh2(q1.x)); c1 = __hadd2(c1, uh2(q1.y));
      c2 = __hadd2(c2, uh2(q1.z)); c3 = __hadd2(c3, uh2(q1.w));
      c0 = __hadd2(c0, uh2(q2.x)); c1 = __hadd2(c1, uh2(q2.y));
      c2 = __hadd2(c2, uh2(q2.z)); c3 = __hadd2(c3, uh2(q2.w));
      c0 = __hadd2(c0, uh2(q3.x)); c1 = __hadd2(c1, uh2(q3.y));
      c2 = __hadd2(c2, uh2(q3.z)); c3 = __hadd2(c3, uh2(q3.w));
    }
    for (; e < end; e += 4) {
      const uint4 q = hv[(size_t)se[e] * 4 + qi];
      c0 = __hadd2(c0, uh2(q.x)); c1 = __hadd2(c1, uh2(q.y));
      c2 = __hadd2(c2, uh2(q.z)); c3 = __hadd2(c3, uh2(q.w));
    }
  } else {
    const int beg = rbeg[node], end = rend[node];
    int e = beg + grp;
    for (; e + 12 < end; e += 16) {
      const int s0 = edata[e], s1 = edata[e + 4], s2 = edata[e + 8], s3 = edata[e + 12];
      const uint4 q0 = hv[(size_t)s0 * 4 + qi];
      const uint4 q1 = hv[(size_t)s1 * 4 + qi];
      const uint4 q2 = hv[(size_t)s2 * 4 + qi];
      const uint4 q3 = hv[(size_t)s3 * 4 + qi];
      c0 = __hadd2(c0, uh2(q0.x)); c1 = __hadd2(c1, uh2(q0.y));
      c2 = __hadd2(c2, uh2(q0.z)); c3 = __hadd2(c3, uh2(q0.w));
      c0 = __hadd2(c0, uh2(q1.x)); c1 = __hadd2(c1, uh2(q1.y));
      c2 = __hadd2(c2, uh2(q1.z)); c3 = __hadd2(c3, uh2(q1.w));
      c0 = __hadd2(c0, uh2(q2.x)); c1 = __hadd2(c1, uh2(q2.y));
      c2 = __hadd2(c2, uh2(q2.z)); c3 = __hadd2(c3, uh2(q2.w));
      c0 = __hadd2(c0, uh2(q3.x)); c1 = __hadd2(c1, uh2(q3.y));
      c2 = __hadd2(c2, uh2(q3.z)); c3 = __hadd2(c3, uh2(q3.w));
    }
    for (; e < end; e += 4) {
      const uint4 q = hv[(size_t)edata[e] * 4 + qi];
      c0 = __hadd2(c0, uh2(q.x)); c1 = __hadd2(c1, uh2(q.y));
      c2 = __hadd2(c2, uh2(q.z)); c3 = __hadd2(c3, uh2(q.w));
    }
  }
#pragma unroll
  for (int m = 4; m <= 8; m <<= 1) {
    c0 = __hadd2(c0, h2shfl_xor(c0, m));
    c1 = __hadd2(c1, h2shfl_xor(c1, m));
    c2 = __hadd2(c2, h2shfl_xor(c2, m));
    c3 = __hadd2(c3, h2shfl_xor(c3, m));
  }
  if (grp != 0) return;
  // self term
  {
    const uint4 q = hv[(size_t)node * 4 + qi];
    c0 = __hadd2(c0, uh2(q.x)); c1 = __hadd2(c1, uh2(q.y));
    c2 = __hadd2(c2, uh2(q.z)); c3 = __hadd2(c3, uh2(q.w));
  }
  const float dn = dinv[node];
  const float2 f0 = h22f2(c0), f1 = h22f2(c1);
  const float2 f2 = h22f2(c2), f3 = h22f2(c3);
  const float v[8] = {f0.x * dn, f0.y * dn, f1.x * dn, f1.y * dn,
                      f2.x * dn, f2.y * dn, f3.x * dn, f3.y * dn};
  float l0 = 0.0f, l1 = 0.0f;
#pragma unroll
  for (int j = 0; j < 8; ++j) {
    const int c = qi * 8 + j;
    float t = v[j] * bn[256 + c] + bn[288 + c];
    t = t > 0.0f ? t : 0.0f;
    const float2 w = *reinterpret_cast<const float2*>(&Wc[c * 2]);
    l0 += t * w.x;
    l1 += t * w.y;
  }
  l0 += __shfl_xor(l0, 1); l1 += __shfl_xor(l1, 1);
  l0 += __shfl_xor(l0, 2); l1 += __shfl_xor(l1, 2);
  if (qi == 0) {
    l0 += bc[0];
    l1 += bc[1];
    const float m = fmaxf(l0, l1);
    const float lse = m + log1pf(expf(-fabsf(l0 - l1)));
    *reinterpret_cast<float2*>(&out[(size_t)node * 2]) = make_float2(l0 - lse, l1 - lse);
  }
}

// ============ launch ============
extern "C" void kernel_launch(void* const* d_in, const int* in_sizes, int n_in,
                              void* d_out, int out_size, void* d_ws, size_t ws_size,
                              hipStream_t stream) {
  const float* x  = (const float*)d_in[0];
  const int* ei   = (const int*)d_in[1];   // int32 on device per harness contract
  const float* W1 = (const float*)d_in[2];
  const float* b1 = (const float*)d_in[3];
  const float* g1 = (const float*)d_in[4];
  const float* be1 = (const float*)d_in[5];
  const float* rm1 = (const float*)d_in[6];
  const float* rv1 = (const float*)d_in[7];
  const float* W2 = (const float*)d_in[8];
  const float* b2 = (const float*)d_in[9];
  const float* g2 = (const float*)d_in[10];
  const float* be2 = (const float*)d_in[11];
  const float* rm2 = (const float*)d_in[12];
  const float* rv2 = (const float*)d_in[13];
  const float* W3 = (const float*)d_in[14];
  const float* b3 = (const float*)d_in[15];
  const float* g3 = (const float*)d_in[16];
  const float* be3 = (const float*)d_in[17];
  const float* rm3 = (const float*)d_in[18];
  const float* rv3 = (const float*)d_in[19];
  const float* Wc = (const float*)d_in[20];
  const float* bc = (const float*)d_in[21];

  const int N_ = in_sizes[0] / 8;
  const int E_ = in_sizes[1] / 2;
  const int NB = (N_ + 255) >> 8;

  auto align = [](size_t v) { return (v + 255) & ~(size_t)255; };
  char* ws = (char*)d_ws;
  size_t off = 0;
  float* dinv   = (float*)(ws + off); off += align((size_t)N_ * 4);
  int* bcur     = (int*)(ws + off);   off += align(((size_t)NB + 1) * 4);
  int* rbeg     = (int*)(ws + off);   off += align((size_t)N_ * 4);
  int* rend     = (int*)(ws + off);   off += align((size_t)N_ * 4);
  float* bnbuf  = (float*)(ws + off); off += align(320 * 4);
  __half2* w2h  = (__half2*)(ws + off); off += align(2048 * 4);
  __half2* w3h  = (__half2*)(ws + off); off += align(1024 * 4);
  int* edata    = (int*)(ws + off);   off += align((size_t)E_ * 4);
  __half* xs    = (__half*)(ws + off); off += align((size_t)N_ * 8 * 2);
  char* regionA = ws + off;           off += align((size_t)NB * BCAP * 4);
  char* regionB = ws + off;           off += align((size_t)N_ * 64 * 2);

  int* bucketbuf = (int*)regionA;
  __half* h3   = (__half*)regionA;   // after p2_sort consumed bucketbuf
  __half* h2   = (__half*)regionB;
  int* gcursor = bcur + NB;

  prep<<<1 + (NB + 1 + 255) / 256, 256, 0, stream>>>(b1, g1, be1, rm1, rv1,
                                                     b2, g2, be2, rm2, rv2,
                                                     b3, g3, be3, rm3, rv3,
                                                     W2, W3, bnbuf, w2h, w3h, bcur, NB);
  p1_partition<<<(E_ + 4095) / 4096, 256, 0, stream>>>(ei, bucketbuf, bcur, E_, NB);
  p2_sort<<<NB, 512, 0, stream>>>(bucketbuf, bcur, gcursor, edata, rbeg, rend,
                                  dinv, x, (__half2*)xs, N_);

  l12<<<(N_ + 31) / 32, 256, 0, stream>>>(xs, dinv, rbeg, rend, edata, W1, w2h, bnbuf, h2, N_);

  gh64_mm3<<<(N_ + 15) / 16, 256, 0, stream>>>(h2, dinv, rbeg, rend, edata, w3h, bnbuf, h3, N_);

  gather_cls<<<(N_ + 15) / 16, 256, 0, stream>>>(h3, dinv, rbeg, rend, edata,
                                                 bnbuf, Wc, bc, (float*)d_out, N_);
}